// Round 2
// baseline (1047.483 us; speedup 1.0000x reference)
//
#include <hip/hip_runtime.h>

#define N_NODES   50000
#define N_EDGES   400000
#define IN_NODE   16
#define OUT_NODE  20
#define IN_EDGE   10
#define HE        64
#define HA        256
#define N_ACT     16
#define N_GRAPHS  128
#define BN_EPS    1e-5f

// ---------------------------------------------------------------------------
// Kernel 1: BN batch statistics over h = edge_attr @ W1 + b1   [E, 64]
// ---------------------------------------------------------------------------
__global__ __launch_bounds__(256) void bn_stats(
    const float* __restrict__ ea, const float* __restrict__ W1,
    const float* __restrict__ b1, float* __restrict__ ssum,
    float* __restrict__ ssq) {
  __shared__ float w1s[IN_EDGE * HE];
  __shared__ float b1s[HE];
  __shared__ float rs[4][HE];
  __shared__ float rq[4][HE];

  const int tid = threadIdx.x;
  for (int t = tid; t < IN_EDGE * HE; t += 256) w1s[t] = W1[t];
  if (tid < HE) b1s[tid] = b1[tid];
  __syncthreads();

  const int c = tid & 63;
  const int r = tid >> 6;  // 0..3
  float s = 0.f, q = 0.f;
  for (int e = blockIdx.x * 4 + r; e < N_EDGES; e += gridDim.x * 4) {
    float h = b1s[c];
#pragma unroll
    for (int k = 0; k < IN_EDGE; ++k) h += ea[e * IN_EDGE + k] * w1s[k * HE + c];
    s += h;
    q += h * h;
  }
  rs[r][c] = s;
  rq[r][c] = q;
  __syncthreads();
  if (tid < HE) {
    float ts = rs[0][tid] + rs[1][tid] + rs[2][tid] + rs[3][tid];
    float tq = rq[0][tid] + rq[1][tid] + rq[2][tid] + rq[3][tid];
    atomicAdd(&ssum[tid], ts);
    atomicAdd(&ssq[tid], tq);
  }
}

// ---------------------------------------------------------------------------
// Kernel 2: finalize BN -> per-channel affine (scale, shift)
// hn = relu(scale*h + shift)
// ---------------------------------------------------------------------------
__global__ void bn_finalize(const float* __restrict__ ssum,
                            const float* __restrict__ ssq,
                            const float* __restrict__ gamma,
                            const float* __restrict__ beta,
                            float* __restrict__ scale,
                            float* __restrict__ shift) {
  int c = threadIdx.x;
  if (c < HE) {
    float mu = ssum[c] * (1.f / (float)N_EDGES);
    float var = ssq[c] * (1.f / (float)N_EDGES) - mu * mu;
    float inv = rsqrtf(var + BN_EPS);
    float sc = gamma[c] * inv;
    scale[c] = sc;
    shift[c] = beta[c] - mu * sc;
  }
}

// ---------------------------------------------------------------------------
// Kernel 3: main edge kernel.
// Per edge e: hn[64] = relu(scale*(ea@W1+b1)+shift)
//   msg[o] = sum_c hn[c] * (sum_i x[src][i]*W2[c][i*20+o]) + sum_i x[src][i]*b2[i*20+o]
//   atomicAdd into agg[dst][o]
// Block = 256 threads = 4 waves. Lane l owns channel c=l; wave w owns o in
// [5w, 5w+5). W2 slice register-cached: 80 VGPR/lane, loaded once per block.
// Tiles of 64 edges staged through LDS.
// ---------------------------------------------------------------------------
__global__ __launch_bounds__(256, 2) void edge_main(
    const float* __restrict__ x, const int* __restrict__ ei,
    const float* __restrict__ ea, const float* __restrict__ W1g,
    const float* __restrict__ b1g, const float* __restrict__ W2g,
    const float* __restrict__ b2g, const float* __restrict__ scale,
    const float* __restrict__ shift, float* __restrict__ agg) {
  __shared__ float w1s[IN_EDGE * HE];
  __shared__ float b1s[HE], scs[HE], shs[HE];
  __shared__ float b2s[IN_NODE * OUT_NODE];
  __shared__ float ea_s[64 * IN_EDGE];
  __shared__ float x_s[64][IN_NODE];
  __shared__ float hn_s[64][HE];
  __shared__ float b2m_s[64][OUT_NODE];
  __shared__ int dst_s[64];

  const int tid = threadIdx.x;
  const int lane = tid & 63;
  const int w = tid >> 6;  // wave 0..3

  for (int t = tid; t < IN_EDGE * HE; t += 256) w1s[t] = W1g[t];
  if (tid < HE) {
    b1s[tid] = b1g[tid];
    scs[tid] = scale[tid];
    shs[tid] = shift[tid];
  }
  for (int t = tid; t < IN_NODE * OUT_NODE; t += 256) b2s[t] = b2g[t];

  // W2 register slice: w2r[i][j] = W2[lane][i*20 + w*5 + j]
  float w2r[IN_NODE][5];
#pragma unroll
  for (int i = 0; i < IN_NODE; ++i)
#pragma unroll
    for (int j = 0; j < 5; ++j)
      w2r[i][j] = W2g[lane * (IN_NODE * OUT_NODE) + i * OUT_NODE + w * 5 + j];

  const int ntiles = N_EDGES / 64;  // 6250, exact
  for (int tile = blockIdx.x; tile < ntiles; tile += gridDim.x) {
    const int e0 = tile * 64;
    __syncthreads();  // previous tile phase-2 done before overwriting LDS

    if (tid < 64) dst_s[tid] = ei[N_EDGES + e0 + tid];
    // edge_attr tile: 640 contiguous floats
    for (int t = tid; t < 64 * IN_EDGE; t += 256) ea_s[t] = ea[e0 * IN_EDGE + t];
    // x gather: 4 threads per edge, one float4 each
    {
      const int e = tid >> 2, qq = tid & 3;
      const int s = ei[e0 + e];
      const float4 v =
          *reinterpret_cast<const float4*>(&x[s * IN_NODE + qq * 4]);
      *reinterpret_cast<float4*>(&x_s[e][qq * 4]) = v;
    }
    __syncthreads();

    // hn for this tile: thread (c=lane) handles edges w, w+4, ...
    for (int e = w; e < 64; e += 4) {
      float h = b1s[lane];
#pragma unroll
      for (int k = 0; k < IN_EDGE; ++k)
        h += ea_s[e * IN_EDGE + k] * w1s[k * HE + lane];
      h = scs[lane] * h + shs[lane];
      hn_s[e][lane] = fmaxf(h, 0.f);
    }
    // per-edge b2 contribution: b2m[e][o] = sum_i x_s[e][i]*b2[i*20+o]
    for (int idx = tid; idx < 64 * OUT_NODE; idx += 256) {
      const int e = idx / OUT_NODE, o = idx % OUT_NODE;
      float v = 0.f;
#pragma unroll
      for (int i = 0; i < IN_NODE; ++i) v += x_s[e][i] * b2s[i * OUT_NODE + o];
      b2m_s[e][o] = v;
    }
    __syncthreads();

    // phase 2: each wave covers all 64 edges for its 5 outputs
    for (int e = 0; e < 64; ++e) {
      const float hn = hn_s[e][lane];
      const float4* xe = reinterpret_cast<const float4*>(x_s[e]);
      const float4 xv0 = xe[0], xv1 = xe[1], xv2 = xe[2], xv3 = xe[3];
      float xf[IN_NODE] = {xv0.x, xv0.y, xv0.z, xv0.w, xv1.x, xv1.y,
                           xv1.z, xv1.w, xv2.x, xv2.y, xv2.z, xv2.w,
                           xv3.x, xv3.y, xv3.z, xv3.w};
      float acc[5] = {0.f, 0.f, 0.f, 0.f, 0.f};
#pragma unroll
      for (int i = 0; i < IN_NODE; ++i) {
        const float ti = hn * xf[i];
#pragma unroll
        for (int j = 0; j < 5; ++j) acc[j] += ti * w2r[i][j];
      }
      // butterfly reduce over 64 lanes (sum over channels)
#pragma unroll
      for (int j = 0; j < 5; ++j) {
        float v = acc[j];
#pragma unroll
        for (int off = 32; off; off >>= 1) v += __shfl_xor(v, off, 64);
        acc[j] = v;
      }
      if (lane == 0) {
        const int d = dst_s[e];
#pragma unroll
        for (int j = 0; j < 5; ++j)
          atomicAdd(&agg[d * OUT_NODE + w * 5 + j],
                    acc[j] + b2m_s[e][w * 5 + j]);
      }
    }
  }
}

// ---------------------------------------------------------------------------
// Kernel 4: out[n] = agg[n] + x[n]@root + bias; pool into per-graph sums
// ---------------------------------------------------------------------------
__global__ __launch_bounds__(256) void node_kernel(
    const float* __restrict__ x, const float* __restrict__ rootg,
    const float* __restrict__ biasg, const int* __restrict__ batch,
    const float* __restrict__ agg, float* __restrict__ psum,
    float* __restrict__ pcnt) {
  __shared__ float roots[IN_NODE * OUT_NODE];
  __shared__ float biass[OUT_NODE];
  // FIX (round 1 -> 2): IN_NODE*OUT_NODE = 320 > 256 threads; the old
  // `if (tid < 320)` guard left roots[256..319] (root rows 13..15) as
  // uninitialized LDS garbage -> ~0.3 absmax error. Use a strided loop.
  for (int t = threadIdx.x; t < IN_NODE * OUT_NODE; t += 256)
    roots[t] = rootg[t];
  if (threadIdx.x < OUT_NODE) biass[threadIdx.x] = biasg[threadIdx.x];
  __syncthreads();

  const int n = blockIdx.x * blockDim.x + threadIdx.x;
  if (n >= N_NODES) return;

  const float4* xp = reinterpret_cast<const float4*>(&x[n * IN_NODE]);
  const float4 a0 = xp[0], a1 = xp[1], a2 = xp[2], a3 = xp[3];
  const float xf[IN_NODE] = {a0.x, a0.y, a0.z, a0.w, a1.x, a1.y, a1.z, a1.w,
                             a2.x, a2.y, a2.z, a2.w, a3.x, a3.y, a3.z, a3.w};
  const int g = batch[n];
  float* ps = &psum[g * OUT_NODE];
#pragma unroll
  for (int o = 0; o < OUT_NODE; ++o) {
    float v = agg[n * OUT_NODE + o] + biass[o];
#pragma unroll
    for (int i = 0; i < IN_NODE; ++i) v += xf[i] * roots[i * OUT_NODE + o];
    atomicAdd(&ps[o], v);
  }
  atomicAdd(&pcnt[g], 1.f);
}

// ---------------------------------------------------------------------------
// Kernel 5: per-graph actor MLP. One block per graph.
// ---------------------------------------------------------------------------
__global__ __launch_bounds__(256) void actor_kernel(
    const float* __restrict__ psum, const float* __restrict__ pcnt,
    const float* __restrict__ A1, const float* __restrict__ ab1,
    const float* __restrict__ A2, const float* __restrict__ ab2,
    float* __restrict__ out) {
  __shared__ float pooled[OUT_NODE];
  __shared__ float a_s[HA];
  __shared__ float red[16][N_ACT];

  const int g = blockIdx.x;
  const int t = threadIdx.x;
  if (t < OUT_NODE) {
    const float c = fmaxf(pcnt[g], 1.f);
    pooled[t] = psum[g * OUT_NODE + t] / c;
  }
  __syncthreads();
  {
    float v = ab1[t];
#pragma unroll
    for (int k = 0; k < OUT_NODE; ++k) v += pooled[k] * A1[k * HA + t];
    a_s[t] = fmaxf(v, 0.f);
  }
  __syncthreads();
  {
    const int j = t & 15, seg = t >> 4;  // 16 segments of 16
    float v = 0.f;
#pragma unroll
    for (int kk = 0; kk < 16; ++kk) {
      const int k = seg * 16 + kk;
      v += a_s[k] * A2[k * N_ACT + j];
    }
    red[seg][j] = v;
  }
  __syncthreads();
  if (t < N_ACT) {
    float s = ab2[t];
#pragma unroll
    for (int seg = 0; seg < 16; ++seg) s += red[seg][t];
    out[g * N_ACT + t] = s;
  }
}

// ---------------------------------------------------------------------------
extern "C" void kernel_launch(void* const* d_in, const int* in_sizes, int n_in,
                              void* d_out, int out_size, void* d_ws,
                              size_t ws_size, hipStream_t stream) {
  const float* x     = (const float*)d_in[0];
  const int*   ei    = (const int*)d_in[1];
  const float* ea    = (const float*)d_in[2];
  const int*   batch = (const int*)d_in[3];
  const float* W1    = (const float*)d_in[4];
  const float* b1    = (const float*)d_in[5];
  const float* gamma = (const float*)d_in[6];
  const float* beta  = (const float*)d_in[7];
  const float* W2    = (const float*)d_in[8];
  const float* b2    = (const float*)d_in[9];
  const float* root  = (const float*)d_in[10];
  const float* bias  = (const float*)d_in[11];
  const float* A1    = (const float*)d_in[12];
  const float* ab1   = (const float*)d_in[13];
  const float* A2    = (const float*)d_in[14];
  const float* ab2   = (const float*)d_in[15];
  float* out = (float*)d_out;

  float* ws = (float*)d_ws;
  float* ssum  = ws;                                // 64
  float* ssq   = ws + 64;                           // 64
  float* scale = ws + 128;                          // 64
  float* shift = ws + 192;                          // 64
  float* agg   = ws + 256;                          // N_NODES*OUT_NODE
  float* psum  = agg + (size_t)N_NODES * OUT_NODE;  // N_GRAPHS*OUT_NODE
  float* pcnt  = psum + N_GRAPHS * OUT_NODE;        // N_GRAPHS

  const size_t zero_bytes =
      (256 + (size_t)N_NODES * OUT_NODE + N_GRAPHS * OUT_NODE + N_GRAPHS) *
      sizeof(float);
  hipMemsetAsync(d_ws, 0, zero_bytes, stream);

  bn_stats<<<512, 256, 0, stream>>>(ea, W1, b1, ssum, ssq);
  bn_finalize<<<1, 64, 0, stream>>>(ssum, ssq, gamma, beta, scale, shift);
  edge_main<<<1280, 256, 0, stream>>>(x, ei, ea, W1, b1, W2, b2, scale, shift,
                                      agg);
  node_kernel<<<(N_NODES + 255) / 256, 256, 0, stream>>>(x, root, bias, batch,
                                                         agg, psum, pcnt);
  actor_kernel<<<N_GRAPHS, 256, 0, stream>>>(psum, pcnt, A1, ab1, A2, ab2, out);
}

// Round 3
// 572.552 us; speedup vs baseline: 1.8295x; 1.8295x over previous
//
#include <hip/hip_runtime.h>

#define N_NODES   50000
#define N_EDGES   400000
#define IN_NODE   16
#define OUT_NODE  20
#define IN_EDGE   10
#define HE        64
#define HA        256
#define N_ACT     16
#define N_GRAPHS  128
#define BN_EPS    1e-5f

typedef __attribute__((ext_vector_type(8))) short short8v;
typedef __attribute__((ext_vector_type(4))) float f32x4;

__device__ __forceinline__ unsigned short f2bf(float f) {
  unsigned u = __float_as_uint(f);
  u += 0x7fffu + ((u >> 16) & 1u);  // RNE
  return (unsigned short)(u >> 16);
}

// DPP row_ror add: reduce over the 16 lanes of a DPP row (= quarter-wave).
#define DPP_ROR_ADD(v, CTRL)                                                  \
  ((v) + __int_as_float(__builtin_amdgcn_update_dpp(                          \
             0, __float_as_int(v), (CTRL), 0xF, 0xF, true)))
#define ROW_SUM16(v)                                                          \
  do {                                                                        \
    v = DPP_ROR_ADD(v, 0x128); /* ror 8 */                                    \
    v = DPP_ROR_ADD(v, 0x124); /* ror 4 */                                    \
    v = DPP_ROR_ADD(v, 0x122); /* ror 2 */                                    \
    v = DPP_ROR_ADD(v, 0x121); /* ror 1 */                                    \
  } while (0)

// ---------------------------------------------------------------------------
// Kernel 1: BN batch statistics over h = edge_attr @ W1 + b1   [E, 64]
// ---------------------------------------------------------------------------
__global__ __launch_bounds__(256) void bn_stats(
    const float* __restrict__ ea, const float* __restrict__ W1,
    const float* __restrict__ b1, float* __restrict__ ssum,
    float* __restrict__ ssq) {
  __shared__ float w1s[IN_EDGE * HE];
  __shared__ float b1s[HE];
  __shared__ float rs[4][HE];
  __shared__ float rq[4][HE];

  const int tid = threadIdx.x;
  for (int t = tid; t < IN_EDGE * HE; t += 256) w1s[t] = W1[t];
  if (tid < HE) b1s[tid] = b1[tid];
  __syncthreads();

  const int c = tid & 63;
  const int r = tid >> 6;
  float s = 0.f, q = 0.f;
  for (int e = blockIdx.x * 4 + r; e < N_EDGES; e += gridDim.x * 4) {
    float h = b1s[c];
#pragma unroll
    for (int k = 0; k < IN_EDGE; ++k) h += ea[e * IN_EDGE + k] * w1s[k * HE + c];
    s += h;
    q += h * h;
  }
  rs[r][c] = s;
  rq[r][c] = q;
  __syncthreads();
  if (tid < HE) {
    float ts = rs[0][tid] + rs[1][tid] + rs[2][tid] + rs[3][tid];
    float tq = rq[0][tid] + rq[1][tid] + rq[2][tid] + rq[3][tid];
    atomicAdd(&ssum[tid], ts);
    atomicAdd(&ssq[tid], tq);
  }
}

// ---------------------------------------------------------------------------
// Kernel 2: finalize BN -> per-channel affine (scale, shift)
// ---------------------------------------------------------------------------
__global__ void bn_finalize(const float* __restrict__ ssum,
                            const float* __restrict__ ssq,
                            const float* __restrict__ gamma,
                            const float* __restrict__ beta,
                            float* __restrict__ scale,
                            float* __restrict__ shift) {
  int c = threadIdx.x;
  if (c < HE) {
    float mu = ssum[c] * (1.f / (float)N_EDGES);
    float var = ssq[c] * (1.f / (float)N_EDGES) - mu * mu;
    float inv = rsqrtf(var + BN_EPS);
    float sc = gamma[c] * inv;
    scale[c] = sc;
    shift[c] = beta[c] - mu * sc;
  }
}

// ---------------------------------------------------------------------------
// Kernel 3: MFMA edge kernel. Tile = 64 edges, 256 threads = 4 waves.
//  GEMM y[64,320'] = hn_bf16[64,64] @ W2'[64,320'] with reordered columns
//  io' = o*16+i, so each 16-wide N-tile is one o with i = lane&15 in the
//  MFMA C layout (col=lane&15, row=(lane>>4)*4+reg). b2 folds into C-in.
//  Then msg[e][o] = sum_i x[e][i]*y -> 16-lane DPP row reduction, atomic out.
//  Wave w owns o in {w, w+4, ..., w+16} (5 N-tiles) x 4 M-tiles x K=64.
// ---------------------------------------------------------------------------
__global__ __launch_bounds__(256, 2) void edge_main(
    const float* __restrict__ x, const int* __restrict__ ei,
    const float* __restrict__ ea, const float* __restrict__ W1g,
    const float* __restrict__ b1g, const float* __restrict__ W2g,
    const float* __restrict__ b2g, const float* __restrict__ scale,
    const float* __restrict__ shift, float* __restrict__ agg) {
  __shared__ short hnb[64 * 72];     // bf16 hn tile, row stride 72 (pad)
  __shared__ float x_s[64 * 20];     // gathered x, row stride 20 (pad)
  __shared__ float ea_s[64 * 10];    // edge_attr tile
  __shared__ float w1t[64 * 11];     // W1^T [c][k], stride 11
  __shared__ float affb1[HE], affsc[HE], affsh[HE];
  __shared__ int dst_s[64];

  const int tid = threadIdx.x;
  const int lane = tid & 63;
  const int w = tid >> 6;          // wave 0..3
  const int i_col = lane & 15;     // MFMA col = i index
  const int kq = lane >> 4;        // quarter 0..3

  // one-time staging: W1^T + BN affine
  for (int t = tid; t < HE * IN_EDGE; t += 256) {
    int c = t & 63, k = t >> 6;
    w1t[c * 11 + k] = W1g[k * HE + c];
  }
  if (tid < HE) {
    affb1[tid] = b1g[tid];
    affsc[tid] = scale[tid];
    affsh[tid] = shift[tid];
  }
  __syncthreads();

  // per-lane W1 row (lane = channel c) + folded affine
  float w1r[IN_EDGE];
#pragma unroll
  for (int k = 0; k < IN_EDGE; ++k) w1r[k] = w1t[lane * 11 + k];
  const float scr = affsc[lane];
  const float c1 = scr * affb1[lane] + affsh[lane];  // scale*b1 + shift

  // B fragments (W2 reordered, bf16) + b2 fold, register-resident
  short8v bfrag[5][2];
  float bias2[5];
#pragma unroll
  for (int t = 0; t < 5; ++t) {
    const int o = w + 4 * t;
    bias2[t] = b2g[i_col * OUT_NODE + o];
#pragma unroll
    for (int ks = 0; ks < 2; ++ks) {
      short8v bv;
#pragma unroll
      for (int j = 0; j < 8; ++j) {
        const int k = ks * 32 + kq * 8 + j;
        bv[j] = (short)f2bf(W2g[k * (IN_NODE * OUT_NODE) + i_col * OUT_NODE + o]);
      }
      bfrag[t][ks] = bv;
    }
  }

  const int ntiles = N_EDGES / 64;  // 6250
  for (int tile = blockIdx.x; tile < ntiles; tile += gridDim.x) {
    const int e0 = tile * 64;
    __syncthreads();  // phase-3 of previous tile done before restaging

    if (tid < 64) dst_s[tid] = ei[N_EDGES + e0 + tid];
    for (int t = tid; t < 64 * IN_EDGE; t += 256) ea_s[t] = ea[e0 * IN_EDGE + t];
    {
      const int e = tid >> 2, q = tid & 3;
      const int s = ei[e0 + e];
      *reinterpret_cast<float4*>(&x_s[e * 20 + q * 4]) =
          *reinterpret_cast<const float4*>(&x[s * IN_NODE + q * 4]);
    }
    __syncthreads();

    // hn (bf16) for this tile: lane = channel, wave w does edges 16w..16w+15
    for (int eo = 0; eo < 16; ++eo) {
      const int e = w * 16 + eo;
      const float2* eap = reinterpret_cast<const float2*>(&ea_s[e * IN_EDGE]);
      const float2 p0 = eap[0], p1 = eap[1], p2 = eap[2], p3 = eap[3],
                   p4 = eap[4];
      float a = p0.x * w1r[0];
      a = fmaf(p0.y, w1r[1], a);
      a = fmaf(p1.x, w1r[2], a);
      a = fmaf(p1.y, w1r[3], a);
      a = fmaf(p2.x, w1r[4], a);
      a = fmaf(p2.y, w1r[5], a);
      a = fmaf(p3.x, w1r[6], a);
      a = fmaf(p3.y, w1r[7], a);
      a = fmaf(p4.x, w1r[8], a);
      a = fmaf(p4.y, w1r[9], a);
      const float hn = fmaxf(fmaf(scr, a, c1), 0.f);
      hnb[e * 72 + lane] = (short)f2bf(hn);
    }
    __syncthreads();

    // MFMA: acc[t][m] = hn(m-tile) @ W2'(o-tile t), C-in = b2'
    f32x4 acc[5][4];
#pragma unroll
    for (int t = 0; t < 5; ++t)
#pragma unroll
      for (int m = 0; m < 4; ++m)
        acc[t][m] = f32x4{bias2[t], bias2[t], bias2[t], bias2[t]};

#pragma unroll
    for (int ks = 0; ks < 2; ++ks) {
      short8v a[4];
#pragma unroll
      for (int m = 0; m < 4; ++m)
        a[m] = *reinterpret_cast<const short8v*>(
            &hnb[(m * 16 + i_col) * 72 + ks * 32 + kq * 8]);
#pragma unroll
      for (int t = 0; t < 5; ++t)
#pragma unroll
        for (int m = 0; m < 4; ++m)
          acc[t][m] = __builtin_amdgcn_mfma_f32_16x16x32_bf16(
              a[m], bfrag[t][ks], acc[t][m], 0, 0, 0);
    }

    // phase 3: msg[e][o] = sum_i x[e][i]*y[e][o*16+i]; DPP 16-lane reduce
#pragma unroll
    for (int t = 0; t < 5; ++t) {
      const int o = w + 4 * t;
#pragma unroll
      for (int m = 0; m < 4; ++m) {
        const int eb = m * 16 + kq * 4;
        float r0 = acc[t][m][0] * x_s[(eb + 0) * 20 + i_col];
        float r1 = acc[t][m][1] * x_s[(eb + 1) * 20 + i_col];
        float r2 = acc[t][m][2] * x_s[(eb + 2) * 20 + i_col];
        float r3 = acc[t][m][3] * x_s[(eb + 3) * 20 + i_col];
        ROW_SUM16(r0);
        ROW_SUM16(r1);
        ROW_SUM16(r2);
        ROW_SUM16(r3);
        if (i_col == 0) {
          atomicAdd(&agg[dst_s[eb + 0] * OUT_NODE + o], r0);
          atomicAdd(&agg[dst_s[eb + 1] * OUT_NODE + o], r1);
          atomicAdd(&agg[dst_s[eb + 2] * OUT_NODE + o], r2);
          atomicAdd(&agg[dst_s[eb + 3] * OUT_NODE + o], r3);
        }
      }
    }
  }
}

// ---------------------------------------------------------------------------
// Kernel 4: out[n] = agg[n] + x[n]@root + bias; pool per graph.
// batch is sorted -> most waves are graph-uniform: wave-reduce + 21 atomics
// per wave instead of 21 per thread.
// ---------------------------------------------------------------------------
__global__ __launch_bounds__(256) void node_kernel(
    const float* __restrict__ x, const float* __restrict__ rootg,
    const float* __restrict__ biasg, const int* __restrict__ batch,
    const float* __restrict__ agg, float* __restrict__ psum,
    float* __restrict__ pcnt) {
  __shared__ float roots[IN_NODE * OUT_NODE];
  __shared__ float biass[OUT_NODE];
  for (int t = threadIdx.x; t < IN_NODE * OUT_NODE; t += 256)
    roots[t] = rootg[t];
  if (threadIdx.x < OUT_NODE) biass[threadIdx.x] = biasg[threadIdx.x];
  __syncthreads();

  const int n = blockIdx.x * blockDim.x + threadIdx.x;
  const int lane = threadIdx.x & 63;
  const bool valid = n < N_NODES;

  float v[OUT_NODE];
  int g = -1;
  if (valid) {
    g = batch[n];
    const float4* xp = reinterpret_cast<const float4*>(&x[n * IN_NODE]);
    const float4 a0 = xp[0], a1 = xp[1], a2 = xp[2], a3 = xp[3];
    const float xf[IN_NODE] = {a0.x, a0.y, a0.z, a0.w, a1.x, a1.y, a1.z, a1.w,
                               a2.x, a2.y, a2.z, a2.w, a3.x, a3.y, a3.z, a3.w};
#pragma unroll
    for (int o = 0; o < OUT_NODE; ++o) {
      float s = agg[n * OUT_NODE + o] + biass[o];
#pragma unroll
      for (int i = 0; i < IN_NODE; ++i) s += xf[i] * roots[i * OUT_NODE + o];
      v[o] = s;
    }
  } else {
#pragma unroll
    for (int o = 0; o < OUT_NODE; ++o) v[o] = 0.f;
  }

  const int g0 = __builtin_amdgcn_readfirstlane(g);
  const bool uni =
      (__ballot(valid && (g == g0)) == 0xFFFFFFFFFFFFFFFFull);

  if (uni) {
#pragma unroll
    for (int o = 0; o < OUT_NODE; ++o) {
      float s = v[o];
      ROW_SUM16(s);
      s += __shfl_xor(s, 16, 64);
      s += __shfl_xor(s, 32, 64);
      v[o] = s;
    }
    if (lane == 0) {
#pragma unroll
      for (int o = 0; o < OUT_NODE; ++o) atomicAdd(&psum[g0 * OUT_NODE + o], v[o]);
      atomicAdd(&pcnt[g0], 64.f);
    }
  } else if (valid) {
#pragma unroll
    for (int o = 0; o < OUT_NODE; ++o) atomicAdd(&psum[g * OUT_NODE + o], v[o]);
    atomicAdd(&pcnt[g], 1.f);
  }
}

// ---------------------------------------------------------------------------
// Kernel 5: per-graph actor MLP. One block per graph.
// ---------------------------------------------------------------------------
__global__ __launch_bounds__(256) void actor_kernel(
    const float* __restrict__ psum, const float* __restrict__ pcnt,
    const float* __restrict__ A1, const float* __restrict__ ab1,
    const float* __restrict__ A2, const float* __restrict__ ab2,
    float* __restrict__ out) {
  __shared__ float pooled[OUT_NODE];
  __shared__ float a_s[HA];
  __shared__ float red[16][N_ACT];

  const int g = blockIdx.x;
  const int t = threadIdx.x;
  if (t < OUT_NODE) {
    const float c = fmaxf(pcnt[g], 1.f);
    pooled[t] = psum[g * OUT_NODE + t] / c;
  }
  __syncthreads();
  {
    float v = ab1[t];
#pragma unroll
    for (int k = 0; k < OUT_NODE; ++k) v += pooled[k] * A1[k * HA + t];
    a_s[t] = fmaxf(v, 0.f);
  }
  __syncthreads();
  {
    const int j = t & 15, seg = t >> 4;
    float v = 0.f;
#pragma unroll
    for (int kk = 0; kk < 16; ++kk) {
      const int k = seg * 16 + kk;
      v += a_s[k] * A2[k * N_ACT + j];
    }
    red[seg][j] = v;
  }
  __syncthreads();
  if (t < N_ACT) {
    float s = ab2[t];
#pragma unroll
    for (int seg = 0; seg < 16; ++seg) s += red[seg][t];
    out[g * N_ACT + t] = s;
  }
}

// ---------------------------------------------------------------------------
extern "C" void kernel_launch(void* const* d_in, const int* in_sizes, int n_in,
                              void* d_out, int out_size, void* d_ws,
                              size_t ws_size, hipStream_t stream) {
  const float* x     = (const float*)d_in[0];
  const int*   ei    = (const int*)d_in[1];
  const float* ea    = (const float*)d_in[2];
  const int*   batch = (const int*)d_in[3];
  const float* W1    = (const float*)d_in[4];
  const float* b1    = (const float*)d_in[5];
  const float* gamma = (const float*)d_in[6];
  const float* beta  = (const float*)d_in[7];
  const float* W2    = (const float*)d_in[8];
  const float* b2    = (const float*)d_in[9];
  const float* root  = (const float*)d_in[10];
  const float* bias  = (const float*)d_in[11];
  const float* A1    = (const float*)d_in[12];
  const float* ab1   = (const float*)d_in[13];
  const float* A2    = (const float*)d_in[14];
  const float* ab2   = (const float*)d_in[15];
  float* out = (float*)d_out;

  float* ws = (float*)d_ws;
  float* ssum  = ws;                                // 64
  float* ssq   = ws + 64;                           // 64
  float* scale = ws + 128;                          // 64
  float* shift = ws + 192;                          // 64
  float* agg   = ws + 256;                          // N_NODES*OUT_NODE
  float* psum  = agg + (size_t)N_NODES * OUT_NODE;  // N_GRAPHS*OUT_NODE
  float* pcnt  = psum + N_GRAPHS * OUT_NODE;        // N_GRAPHS

  const size_t zero_bytes =
      (256 + (size_t)N_NODES * OUT_NODE + N_GRAPHS * OUT_NODE + N_GRAPHS) *
      sizeof(float);
  hipMemsetAsync(d_ws, 0, zero_bytes, stream);

  bn_stats<<<512, 256, 0, stream>>>(ea, W1, b1, ssum, ssq);
  bn_finalize<<<1, 64, 0, stream>>>(ssum, ssq, gamma, beta, scale, shift);
  edge_main<<<2048, 256, 0, stream>>>(x, ei, ea, W1, b1, W2, b2, scale, shift,
                                      agg);
  node_kernel<<<(N_NODES + 255) / 256, 256, 0, stream>>>(x, root, bias, batch,
                                                         agg, psum, pcnt);
  actor_kernel<<<N_GRAPHS, 256, 0, stream>>>(psum, pcnt, A1, ab1, A2, ab2, out);
}

// Round 4
// 261.559 us; speedup vs baseline: 4.0048x; 2.1890x over previous
//
#include <hip/hip_runtime.h>

#define N_NODES   50000
#define N_EDGES   400000
#define IN_NODE   16
#define OUT_NODE  20
#define IN_EDGE   10
#define HE        64
#define HA        256
#define N_ACT     16
#define N_GRAPHS  128
#define BN_EPS    1e-5f
#define EDGE_GRID 512

typedef __attribute__((ext_vector_type(8))) short short8v;
typedef __attribute__((ext_vector_type(4))) float f32x4;

__device__ __forceinline__ unsigned short f2bf(float f) {
  unsigned u = __float_as_uint(f);
  u += 0x7fffu + ((u >> 16) & 1u);  // RNE
  return (unsigned short)(u >> 16);
}

// DPP row_ror add: reduce over the 16 lanes of a DPP row (= quarter-wave).
#define DPP_ROR_ADD(v, CTRL)                                                  \
  ((v) + __int_as_float(__builtin_amdgcn_update_dpp(                          \
             0, __float_as_int(v), (CTRL), 0xF, 0xF, true)))
#define ROW_SUM16(v)                                                          \
  do {                                                                        \
    v = DPP_ROR_ADD(v, 0x128); /* ror 8 */                                    \
    v = DPP_ROR_ADD(v, 0x124); /* ror 4 */                                    \
    v = DPP_ROR_ADD(v, 0x122); /* ror 2 */                                    \
    v = DPP_ROR_ADD(v, 0x121); /* ror 1 */                                    \
  } while (0)

// ---------------------------------------------------------------------------
// Kernel 1: BN batch statistics over h = edge_attr @ W1 + b1   [E, 64]
// ---------------------------------------------------------------------------
__global__ __launch_bounds__(256) void bn_stats(
    const float* __restrict__ ea, const float* __restrict__ W1,
    const float* __restrict__ b1, float* __restrict__ ssum,
    float* __restrict__ ssq) {
  __shared__ float w1s[IN_EDGE * HE];
  __shared__ float b1s[HE];
  __shared__ float rs[4][HE];
  __shared__ float rq[4][HE];

  const int tid = threadIdx.x;
  for (int t = tid; t < IN_EDGE * HE; t += 256) w1s[t] = W1[t];
  if (tid < HE) b1s[tid] = b1[tid];
  __syncthreads();

  const int c = tid & 63;
  const int r = tid >> 6;
  float s = 0.f, q = 0.f;
  for (int e = blockIdx.x * 4 + r; e < N_EDGES; e += gridDim.x * 4) {
    float h = b1s[c];
#pragma unroll
    for (int k = 0; k < IN_EDGE; ++k) h += ea[e * IN_EDGE + k] * w1s[k * HE + c];
    s += h;
    q += h * h;
  }
  rs[r][c] = s;
  rq[r][c] = q;
  __syncthreads();
  if (tid < HE) {
    float ts = rs[0][tid] + rs[1][tid] + rs[2][tid] + rs[3][tid];
    float tq = rq[0][tid] + rq[1][tid] + rq[2][tid] + rq[3][tid];
    atomicAdd(&ssum[tid], ts);
    atomicAdd(&ssq[tid], tq);
  }
}

// ---------------------------------------------------------------------------
// Kernel 2: finalize BN -> per-channel affine (scale, shift)
// ---------------------------------------------------------------------------
__global__ void bn_finalize(const float* __restrict__ ssum,
                            const float* __restrict__ ssq,
                            const float* __restrict__ gamma,
                            const float* __restrict__ beta,
                            float* __restrict__ scale,
                            float* __restrict__ shift) {
  int c = threadIdx.x;
  if (c < HE) {
    float mu = ssum[c] * (1.f / (float)N_EDGES);
    float var = ssq[c] * (1.f / (float)N_EDGES) - mu * mu;
    float inv = rsqrtf(var + BN_EPS);
    float sc = gamma[c] * inv;
    scale[c] = sc;
    shift[c] = beta[c] - mu * sc;
  }
}

// ---------------------------------------------------------------------------
// Kernel 3: MFMA edge kernel. Tile = 64 edges, 256 threads = 4 waves.
//  GEMM y[64,320'] = hn_bf16[64,64] @ W2'[64,320'] (columns io'=o*16+i) via
//  mfma_f32_16x16x32_bf16; C layout col=lane&15 (=i), row=kq*4+reg (=edge).
//  b2 folds into C-in. msg[e][o] = sum_i x[e][i]*y -> 16-lane DPP reduce.
//  R4: agg[n] eliminated (output only needs per-graph pools) ->
//  ds_add_f32 into LDS psum[128][20], block-partial flush to part[b][2560].
//  No global atomics in the hot path (was 8M x 32B writes = 250 MB = bound).
// ---------------------------------------------------------------------------
__global__ __launch_bounds__(256, 2) void edge_main(
    const float* __restrict__ x, const int* __restrict__ ei,
    const float* __restrict__ ea, const float* __restrict__ W1g,
    const float* __restrict__ b1g, const float* __restrict__ W2g,
    const float* __restrict__ b2g, const float* __restrict__ scale,
    const float* __restrict__ shift, const int* __restrict__ batch,
    float* __restrict__ part) {
  __shared__ float psum_lds[N_GRAPHS * OUT_NODE];  // 2560 floats
  __shared__ short hnb[64 * 72];     // bf16 hn tile, row stride 72 (pad)
  __shared__ float x_s[64 * 20];     // gathered x, row stride 20 (pad)
  __shared__ float ea_s[64 * 10];    // edge_attr tile
  __shared__ float w1t[64 * 11];     // W1^T [c][k], stride 11
  __shared__ float affb1[HE], affsc[HE], affsh[HE];
  __shared__ int g_s[64];            // graph of dst node per edge

  const int tid = threadIdx.x;
  const int lane = tid & 63;
  const int w = tid >> 6;          // wave 0..3
  const int i_col = lane & 15;     // MFMA col = i index
  const int kq = lane >> 4;        // quarter 0..3

  for (int t = tid; t < N_GRAPHS * OUT_NODE; t += 256) psum_lds[t] = 0.f;
  for (int t = tid; t < HE * IN_EDGE; t += 256) {
    int c = t & 63, k = t >> 6;
    w1t[c * 11 + k] = W1g[k * HE + c];
  }
  if (tid < HE) {
    affb1[tid] = b1g[tid];
    affsc[tid] = scale[tid];
    affsh[tid] = shift[tid];
  }
  __syncthreads();

  float w1r[IN_EDGE];
#pragma unroll
  for (int k = 0; k < IN_EDGE; ++k) w1r[k] = w1t[lane * 11 + k];
  const float scr = affsc[lane];
  const float c1 = scr * affb1[lane] + affsh[lane];  // scale*b1 + shift

  // B fragments (W2 reordered, bf16) + b2 fold, register-resident
  short8v bfrag[5][2];
  float bias2[5];
#pragma unroll
  for (int t = 0; t < 5; ++t) {
    const int o = w + 4 * t;
    bias2[t] = b2g[i_col * OUT_NODE + o];
#pragma unroll
    for (int ks = 0; ks < 2; ++ks) {
      short8v bv;
#pragma unroll
      for (int j = 0; j < 8; ++j) {
        const int k = ks * 32 + kq * 8 + j;
        bv[j] = (short)f2bf(W2g[k * (IN_NODE * OUT_NODE) + i_col * OUT_NODE + o]);
      }
      bfrag[t][ks] = bv;
    }
  }

  const int ntiles = N_EDGES / 64;  // 6250
  for (int tile = blockIdx.x; tile < ntiles; tile += gridDim.x) {
    const int e0 = tile * 64;
    __syncthreads();  // phase-3 of previous tile done before restaging

    if (tid < 64) g_s[tid] = batch[ei[N_EDGES + e0 + tid]];
    for (int t = tid; t < 64 * IN_EDGE; t += 256) ea_s[t] = ea[e0 * IN_EDGE + t];
    {
      const int e = tid >> 2, q = tid & 3;
      const int s = ei[e0 + e];
      *reinterpret_cast<float4*>(&x_s[e * 20 + q * 4]) =
          *reinterpret_cast<const float4*>(&x[s * IN_NODE + q * 4]);
    }
    __syncthreads();

    // hn (bf16): lane = channel, wave w does edges 16w..16w+15
    for (int eo = 0; eo < 16; ++eo) {
      const int e = w * 16 + eo;
      const float2* eap = reinterpret_cast<const float2*>(&ea_s[e * IN_EDGE]);
      const float2 p0 = eap[0], p1 = eap[1], p2 = eap[2], p3 = eap[3],
                   p4 = eap[4];
      float a = p0.x * w1r[0];
      a = fmaf(p0.y, w1r[1], a);
      a = fmaf(p1.x, w1r[2], a);
      a = fmaf(p1.y, w1r[3], a);
      a = fmaf(p2.x, w1r[4], a);
      a = fmaf(p2.y, w1r[5], a);
      a = fmaf(p3.x, w1r[6], a);
      a = fmaf(p3.y, w1r[7], a);
      a = fmaf(p4.x, w1r[8], a);
      a = fmaf(p4.y, w1r[9], a);
      const float hn = fmaxf(fmaf(scr, a, c1), 0.f);
      hnb[e * 72 + lane] = (short)f2bf(hn);
    }
    __syncthreads();

    // MFMA: acc[t][m] = hn(m-tile) @ W2'(o-tile t), C-in = b2'
    f32x4 acc[5][4];
#pragma unroll
    for (int t = 0; t < 5; ++t)
#pragma unroll
      for (int m = 0; m < 4; ++m)
        acc[t][m] = f32x4{bias2[t], bias2[t], bias2[t], bias2[t]};

#pragma unroll
    for (int ks = 0; ks < 2; ++ks) {
      short8v a[4];
#pragma unroll
      for (int m = 0; m < 4; ++m)
        a[m] = *reinterpret_cast<const short8v*>(
            &hnb[(m * 16 + i_col) * 72 + ks * 32 + kq * 8]);
#pragma unroll
      for (int t = 0; t < 5; ++t)
#pragma unroll
        for (int m = 0; m < 4; ++m)
          acc[t][m] = __builtin_amdgcn_mfma_f32_16x16x32_bf16(
              a[m], bfrag[t][ks], acc[t][m], 0, 0, 0);
    }

    // phase 3: msg[e][o] = sum_i x[e][i]*y; DPP reduce; LDS atomic to graph
#pragma unroll
    for (int m = 0; m < 4; ++m) {
      const int eb = m * 16 + kq * 4;
      const float xv0 = x_s[(eb + 0) * 20 + i_col];
      const float xv1 = x_s[(eb + 1) * 20 + i_col];
      const float xv2 = x_s[(eb + 2) * 20 + i_col];
      const float xv3 = x_s[(eb + 3) * 20 + i_col];
      const int gsel = g_s[eb + (i_col & 3)];
#pragma unroll
      for (int t = 0; t < 5; ++t) {
        const int o = w + 4 * t;
        float r0 = acc[t][m][0] * xv0;
        float r1 = acc[t][m][1] * xv1;
        float r2 = acc[t][m][2] * xv2;
        float r3 = acc[t][m][3] * xv3;
        ROW_SUM16(r0);
        ROW_SUM16(r1);
        ROW_SUM16(r2);
        ROW_SUM16(r3);
        // lanes i_col 0..3 of each quarter write edges eb+0..3
        float rv = (i_col == 0) ? r0
                 : (i_col == 1) ? r1
                 : (i_col == 2) ? r2 : r3;
        if (i_col < 4) atomicAdd(&psum_lds[gsel * OUT_NODE + o], rv);
      }
    }
  }

  __syncthreads();
  // flush block partial (plain coalesced stores, no global atomics)
  for (int t = tid; t < N_GRAPHS * OUT_NODE; t += 256)
    part[(size_t)blockIdx.x * (N_GRAPHS * OUT_NODE) + t] = psum_lds[t];
}

// ---------------------------------------------------------------------------
// Kernel 3b: reduce block partials into psum. 2560 outputs x 8 slices.
// ---------------------------------------------------------------------------
__global__ __launch_bounds__(256) void reduce_part(
    const float* __restrict__ part, float* __restrict__ psum) {
  const int j = blockIdx.x * 256 + threadIdx.x;  // 0..20479
  const int idx = j >> 3, sl = j & 7;
  float s = 0.f;
  for (int b = sl; b < EDGE_GRID; b += 8)
    s += part[(size_t)b * (N_GRAPHS * OUT_NODE) + idx];
  s += __shfl_xor(s, 1, 64);
  s += __shfl_xor(s, 2, 64);
  s += __shfl_xor(s, 4, 64);
  if (sl == 0) atomicAdd(&psum[idx], s);
}

// ---------------------------------------------------------------------------
// Kernel 4: psum[g] += sum_{n in g} (x[n]@root + bias); pcnt[g] += count.
// batch sorted -> wave-uniform fast path: wave-reduce, 21 atomics per wave.
// ---------------------------------------------------------------------------
__global__ __launch_bounds__(256) void node_kernel(
    const float* __restrict__ x, const float* __restrict__ rootg,
    const float* __restrict__ biasg, const int* __restrict__ batch,
    float* __restrict__ psum, float* __restrict__ pcnt) {
  __shared__ float roots[IN_NODE * OUT_NODE];
  __shared__ float biass[OUT_NODE];
  for (int t = threadIdx.x; t < IN_NODE * OUT_NODE; t += 256)
    roots[t] = rootg[t];
  if (threadIdx.x < OUT_NODE) biass[threadIdx.x] = biasg[threadIdx.x];
  __syncthreads();

  const int n = blockIdx.x * blockDim.x + threadIdx.x;
  const int lane = threadIdx.x & 63;
  const bool valid = n < N_NODES;

  float v[OUT_NODE];
  int g = -1;
  if (valid) {
    g = batch[n];
    const float4* xp = reinterpret_cast<const float4*>(&x[n * IN_NODE]);
    const float4 a0 = xp[0], a1 = xp[1], a2 = xp[2], a3 = xp[3];
    const float xf[IN_NODE] = {a0.x, a0.y, a0.z, a0.w, a1.x, a1.y, a1.z, a1.w,
                               a2.x, a2.y, a2.z, a2.w, a3.x, a3.y, a3.z, a3.w};
#pragma unroll
    for (int o = 0; o < OUT_NODE; ++o) {
      float s = biass[o];
#pragma unroll
      for (int i = 0; i < IN_NODE; ++i) s += xf[i] * roots[i * OUT_NODE + o];
      v[o] = s;
    }
  } else {
#pragma unroll
    for (int o = 0; o < OUT_NODE; ++o) v[o] = 0.f;
  }

  const int g0 = __builtin_amdgcn_readfirstlane(g);
  const bool uni = (__ballot(valid && (g == g0)) == 0xFFFFFFFFFFFFFFFFull);

  if (uni) {
#pragma unroll
    for (int o = 0; o < OUT_NODE; ++o) {
      float s = v[o];
      ROW_SUM16(s);
      s += __shfl_xor(s, 16, 64);
      s += __shfl_xor(s, 32, 64);
      v[o] = s;
    }
    if (lane == 0) {
#pragma unroll
      for (int o = 0; o < OUT_NODE; ++o)
        atomicAdd(&psum[g0 * OUT_NODE + o], v[o]);
      atomicAdd(&pcnt[g0], 64.f);
    }
  } else if (valid) {
#pragma unroll
    for (int o = 0; o < OUT_NODE; ++o) atomicAdd(&psum[g * OUT_NODE + o], v[o]);
    atomicAdd(&pcnt[g], 1.f);
  }
}

// ---------------------------------------------------------------------------
// Kernel 5: per-graph actor MLP. One block per graph.
// ---------------------------------------------------------------------------
__global__ __launch_bounds__(256) void actor_kernel(
    const float* __restrict__ psum, const float* __restrict__ pcnt,
    const float* __restrict__ A1, const float* __restrict__ ab1,
    const float* __restrict__ A2, const float* __restrict__ ab2,
    float* __restrict__ out) {
  __shared__ float pooled[OUT_NODE];
  __shared__ float a_s[HA];
  __shared__ float red[16][N_ACT];

  const int g = blockIdx.x;
  const int t = threadIdx.x;
  if (t < OUT_NODE) {
    const float c = fmaxf(pcnt[g], 1.f);
    pooled[t] = psum[g * OUT_NODE + t] / c;
  }
  __syncthreads();
  {
    float v = ab1[t];
#pragma unroll
    for (int k = 0; k < OUT_NODE; ++k) v += pooled[k] * A1[k * HA + t];
    a_s[t] = fmaxf(v, 0.f);
  }
  __syncthreads();
  {
    const int j = t & 15, seg = t >> 4;
    float v = 0.f;
#pragma unroll
    for (int kk = 0; kk < 16; ++kk) {
      const int k = seg * 16 + kk;
      v += a_s[k] * A2[k * N_ACT + j];
    }
    red[seg][j] = v;
  }
  __syncthreads();
  if (t < N_ACT) {
    float s = ab2[t];
#pragma unroll
    for (int seg = 0; seg < 16; ++seg) s += red[seg][t];
    out[g * N_ACT + t] = s;
  }
}

// ---------------------------------------------------------------------------
extern "C" void kernel_launch(void* const* d_in, const int* in_sizes, int n_in,
                              void* d_out, int out_size, void* d_ws,
                              size_t ws_size, hipStream_t stream) {
  const float* x     = (const float*)d_in[0];
  const int*   ei    = (const int*)d_in[1];
  const float* ea    = (const float*)d_in[2];
  const int*   batch = (const int*)d_in[3];
  const float* W1    = (const float*)d_in[4];
  const float* b1    = (const float*)d_in[5];
  const float* gamma = (const float*)d_in[6];
  const float* beta  = (const float*)d_in[7];
  const float* W2    = (const float*)d_in[8];
  const float* b2    = (const float*)d_in[9];
  const float* root  = (const float*)d_in[10];
  const float* bias  = (const float*)d_in[11];
  const float* A1    = (const float*)d_in[12];
  const float* ab1   = (const float*)d_in[13];
  const float* A2    = (const float*)d_in[14];
  const float* ab2   = (const float*)d_in[15];
  float* out = (float*)d_out;

  float* ws = (float*)d_ws;
  float* ssum  = ws;                          // 64
  float* ssq   = ws + 64;                     // 64
  float* scale = ws + 128;                    // 64
  float* shift = ws + 192;                    // 64
  float* psum  = ws + 256;                    // N_GRAPHS*OUT_NODE = 2560
  float* pcnt  = psum + N_GRAPHS * OUT_NODE;  // 128
  float* partb = pcnt + N_GRAPHS;             // EDGE_GRID*2560 = 5.24 MB

  const size_t zero_bytes =
      (256 + N_GRAPHS * OUT_NODE + N_GRAPHS) * sizeof(float);
  hipMemsetAsync(d_ws, 0, zero_bytes, stream);

  bn_stats<<<512, 256, 0, stream>>>(ea, W1, b1, ssum, ssq);
  bn_finalize<<<1, 64, 0, stream>>>(ssum, ssq, gamma, beta, scale, shift);
  edge_main<<<EDGE_GRID, 256, 0, stream>>>(x, ei, ea, W1, b1, W2, b2, scale,
                                           shift, batch, partb);
  reduce_part<<<80, 256, 0, stream>>>(partb, psum);
  node_kernel<<<(N_NODES + 255) / 256, 256, 0, stream>>>(x, root, bias, batch,
                                                         psum, pcnt);
  actor_kernel<<<N_GRAPHS, 256, 0, stream>>>(psum, pcnt, A1, ab1, A2, ab2, out);
}

// Round 5
// 237.600 us; speedup vs baseline: 4.4086x; 1.1008x over previous
//
#include <hip/hip_runtime.h>

#define N_NODES   50000
#define N_EDGES   400000
#define IN_NODE   16
#define OUT_NODE  20
#define IN_EDGE   10
#define HE        64
#define HA        256
#define N_ACT     16
#define N_GRAPHS  128
#define BN_EPS    1e-5f
#define EDGE_GRID 1024

typedef __attribute__((ext_vector_type(8))) short short8v;
typedef __attribute__((ext_vector_type(4))) float f32x4;

__device__ __forceinline__ unsigned short f2bf(float f) {
  unsigned u = __float_as_uint(f);
  u += 0x7fffu + ((u >> 16) & 1u);  // RNE
  return (unsigned short)(u >> 16);
}

#define DPP_ROR_ADD(v, CTRL)                                                  \
  ((v) + __int_as_float(__builtin_amdgcn_update_dpp(                          \
             0, __float_as_int(v), (CTRL), 0xF, 0xF, true)))
#define ROW_SUM16(v)                                                          \
  do {                                                                        \
    v = DPP_ROR_ADD(v, 0x128);                                                \
    v = DPP_ROR_ADD(v, 0x124);                                                \
    v = DPP_ROR_ADD(v, 0x122);                                                \
    v = DPP_ROR_ADD(v, 0x121);                                                \
  } while (0)

// ---------------------------------------------------------------------------
// Kernel 1: BN stats via Gram trick. h = ea@W1 + b1 is linear in ea, so
//   sum_e h[c]  = colsum(ea)@W1[:,c] + E*b1
//   sum_e h[c]^2 = W1[:,c]^T G W1[:,c] + 2 b1 (colsum@W1) + E b1^2,
// with G = ea^T ea (10x10). One coalesced pass, 65 reduction values.
// hdr layout: [0:10) colsum, [16:71) gram packed (a<=b, row-major).
// ---------------------------------------------------------------------------
__global__ __launch_bounds__(256) void bn_stats(const float* __restrict__ ea,
                                                float* __restrict__ hdr) {
  float cs[10];
  float gm[55];
#pragma unroll
  for (int a = 0; a < 10; ++a) cs[a] = 0.f;
#pragma unroll
  for (int u = 0; u < 55; ++u) gm[u] = 0.f;

  for (int e = blockIdx.x * 256 + threadIdx.x; e < N_EDGES; e += 64 * 256) {
    const float2* rp = reinterpret_cast<const float2*>(ea + (size_t)e * 10);
    float f[10];
#pragma unroll
    for (int p = 0; p < 5; ++p) {
      const float2 t = rp[p];
      f[2 * p] = t.x;
      f[2 * p + 1] = t.y;
    }
#pragma unroll
    for (int a = 0; a < 10; ++a) cs[a] += f[a];
    int idx = 0;
#pragma unroll
    for (int a = 0; a < 10; ++a)
#pragma unroll
      for (int b = a; b < 10; ++b) {
        gm[idx] = fmaf(f[a], f[b], gm[idx]);
        ++idx;
      }
  }

  // wave butterfly
#pragma unroll
  for (int v = 0; v < 10; ++v)
#pragma unroll
    for (int off = 1; off < 64; off <<= 1) cs[v] += __shfl_xor(cs[v], off, 64);
#pragma unroll
  for (int u = 0; u < 55; ++u)
#pragma unroll
    for (int off = 1; off < 64; off <<= 1) gm[u] += __shfl_xor(gm[u], off, 64);

  __shared__ float red[4][72];
  const int lane = threadIdx.x & 63;
  const int w = threadIdx.x >> 6;
  if (lane == 0) {
#pragma unroll
    for (int v = 0; v < 10; ++v) red[w][v] = cs[v];
#pragma unroll
    for (int u = 0; u < 55; ++u) red[w][10 + u] = gm[u];
  }
  __syncthreads();
  if (threadIdx.x < 65) {
    const int t = threadIdx.x;
    const float s = red[0][t] + red[1][t] + red[2][t] + red[3][t];
    const int dst = (t < 10) ? t : 6 + t;  // gram at hdr[16+..]
    atomicAdd(&hdr[dst], s);
  }
}

// ---------------------------------------------------------------------------
// Kernel 2: finalize -> per-channel (scale, c1) with hn = relu(scale*u + c1)
// where u = ea@W1 (no b1; b1 folded into c1).
// ---------------------------------------------------------------------------
__global__ void bn_finalize(const float* __restrict__ hdr,
                            const float* __restrict__ W1,
                            const float* __restrict__ b1,
                            const float* __restrict__ gamma,
                            const float* __restrict__ beta,
                            float* __restrict__ scale,
                            float* __restrict__ c1out) {
  const int c = threadIdx.x;
  if (c >= HE) return;
  float wc[10];
#pragma unroll
  for (int k = 0; k < 10; ++k) wc[k] = W1[k * HE + c];
  float su = 0.f;
#pragma unroll
  for (int k = 0; k < 10; ++k) su = fmaf(hdr[k], wc[k], su);
  float q = 0.f;
  int idx = 0;
#pragma unroll
  for (int a = 0; a < 10; ++a) {
    q = fmaf(hdr[16 + idx], wc[a] * wc[a], q);
    ++idx;
#pragma unroll
    for (int b = a + 1; b < 10; ++b) {
      q = fmaf(2.f * hdr[16 + idx], wc[a] * wc[b], q);
      ++idx;
    }
  }
  const float b1c = b1[c];
  const float invE = 1.f / (float)N_EDGES;
  const float mu = su * invE + b1c;
  const float Eh2 = (q + 2.f * b1c * su) * invE + b1c * b1c;
  const float var = Eh2 - mu * mu;
  const float sc = gamma[c] * rsqrtf(var + BN_EPS);
  scale[c] = sc;
  c1out[c] = sc * (b1c - mu) + beta[c];
}

// ---------------------------------------------------------------------------
// Kernel 3: MFMA edge kernel, 64-edge tiles, 4 waves, 1 barrier/tile.
// Produce (per wave, own 16 edges): ea loaded direct from global as bf16
//   A-frag (K pad 10->32), 4 hn-MFMA vs register W1 frags, affine+relu,
//   16 ds_write_b16 into double-buffered hnb.
// Consume (after barrier): 8 ds_read_b128 A-frags (all 64 edges), 40 MFMA
//   vs register W2' frags (cols io'=o*16+i, b2 in C-in), phase-3 DPP
//   16-lane reduce with x gathered direct from global, ds_add into
//   psum_lds[128][20]; block partial flushed once at end.
// ---------------------------------------------------------------------------
__global__ __launch_bounds__(256, 3) void edge_main(
    const float* __restrict__ x, const int* __restrict__ ei,
    const float* __restrict__ ea, const float* __restrict__ W1g,
    const float* __restrict__ W2g, const float* __restrict__ b2g,
    const float* __restrict__ scale, const float* __restrict__ c1g,
    const int* __restrict__ batch, float* __restrict__ part) {
  __shared__ __align__(16) float psum_lds[N_GRAPHS * OUT_NODE];  // 10 KB
  __shared__ short hnb[2][64 * 68];                              // 2x8.5 KB

  const int tid = threadIdx.x;
  const int lane = tid & 63;
  const int w = tid >> 6;        // wave 0..3
  const int i_col = lane & 15;   // MFMA col lane
  const int kq = lane >> 4;      // quarter 0..3

  for (int t = tid; t < N_GRAPHS * OUT_NODE; t += 256) psum_lds[t] = 0.f;

  // W1 B-frags (bf16, K-padded), per-lane scale/c1 -- once per kernel
  short8v w1f[4];
  float scv[4], c1v[4];
#pragma unroll
  for (int nt = 0; nt < 4; ++nt) {
    short8v v;
#pragma unroll
    for (int j = 0; j < 8; ++j) {
      const int k = kq * 8 + j;
      const float f = (k < IN_EDGE) ? W1g[k * HE + nt * 16 + i_col] : 0.f;
      v[j] = (short)f2bf(f);
    }
    w1f[nt] = v;
    scv[nt] = scale[nt * 16 + i_col];
    c1v[nt] = c1g[nt * 16 + i_col];
  }

  // W2' B-frags + b2 fold
  short8v bfrag[5][2];
  float bias2[5];
#pragma unroll
  for (int t = 0; t < 5; ++t) {
    const int o = w + 4 * t;
    bias2[t] = b2g[i_col * OUT_NODE + o];
#pragma unroll
    for (int ks = 0; ks < 2; ++ks) {
      short8v bv;
#pragma unroll
      for (int j = 0; j < 8; ++j) {
        const int k = ks * 32 + kq * 8 + j;
        bv[j] = (short)f2bf(W2g[k * (IN_NODE * OUT_NODE) + i_col * OUT_NODE + o]);
      }
      bfrag[t][ks] = bv;
    }
  }
  __syncthreads();  // psum_lds zeroed

  int p = 0;
  for (int tile = blockIdx.x; tile < N_EDGES / 64; tile += EDGE_GRID) {
    const int e0 = tile * 64;

    // ---- produce: hn for this wave's 16 edges ----
    {
      const float* row = ea + (size_t)(e0 + w * 16 + i_col) * IN_EDGE;
      float af[8];
#pragma unroll
      for (int j = 0; j < 8; ++j) af[j] = 0.f;
#pragma unroll
      for (int pr = 0; pr < 4; ++pr) {
        const int k = kq * 8 + pr * 2;
        if (k < IN_EDGE) {
          const float2 t2 = *reinterpret_cast<const float2*>(row + k);
          af[pr * 2] = t2.x;
          af[pr * 2 + 1] = t2.y;
        }
      }
      short8v ae;
#pragma unroll
      for (int j = 0; j < 8; ++j) ae[j] = (short)f2bf(af[j]);

      const f32x4 zero4 = {0.f, 0.f, 0.f, 0.f};
#pragma unroll
      for (int nt = 0; nt < 4; ++nt) {
        const f32x4 hv =
            __builtin_amdgcn_mfma_f32_16x16x32_bf16(ae, w1f[nt], zero4, 0, 0, 0);
#pragma unroll
        for (int r = 0; r < 4; ++r) {
          const float hnv = fmaxf(fmaf(hv[r], scv[nt], c1v[nt]), 0.f);
          hnb[p][(w * 16 + kq * 4 + r) * 68 + nt * 16 + i_col] =
              (short)f2bf(hnv);
        }
      }
    }
    __syncthreads();  // hnb[p] complete; prev readers of hnb[p^1] done

    // ---- consume: all 64 edges, this wave's 5 outputs ----
    // gather x / graph ids direct from global (L1/L2-hot)
    float xv[16];
    int gidx[4];
#pragma unroll
    for (int m = 0; m < 4; ++m) {
#pragma unroll
      for (int j = 0; j < 4; ++j) {
        const int s = ei[e0 + m * 16 + kq * 4 + j];
        xv[m * 4 + j] = x[(size_t)s * IN_NODE + i_col];
      }
      gidx[m] = batch[ei[N_EDGES + e0 + m * 16 + kq * 4 + (i_col & 3)]];
    }

    short8v afr[4][2];
#pragma unroll
    for (int m = 0; m < 4; ++m)
#pragma unroll
      for (int ks = 0; ks < 2; ++ks)
        afr[m][ks] = *reinterpret_cast<const short8v*>(
            &hnb[p][(m * 16 + i_col) * 68 + ks * 32 + kq * 8]);

    f32x4 acc[5][4];
#pragma unroll
    for (int t = 0; t < 5; ++t)
#pragma unroll
      for (int m = 0; m < 4; ++m)
        acc[t][m] = f32x4{bias2[t], bias2[t], bias2[t], bias2[t]};

#pragma unroll
    for (int ks = 0; ks < 2; ++ks)
#pragma unroll
      for (int t = 0; t < 5; ++t)
#pragma unroll
        for (int m = 0; m < 4; ++m)
          acc[t][m] = __builtin_amdgcn_mfma_f32_16x16x32_bf16(
              afr[m][ks], bfrag[t][ks], acc[t][m], 0, 0, 0);

#pragma unroll
    for (int t = 0; t < 5; ++t) {
      const int o = w + 4 * t;
#pragma unroll
      for (int m = 0; m < 4; ++m) {
        float r0 = acc[t][m][0] * xv[m * 4 + 0];
        float r1 = acc[t][m][1] * xv[m * 4 + 1];
        float r2 = acc[t][m][2] * xv[m * 4 + 2];
        float r3 = acc[t][m][3] * xv[m * 4 + 3];
        ROW_SUM16(r0);
        ROW_SUM16(r1);
        ROW_SUM16(r2);
        ROW_SUM16(r3);
        const float rv = (i_col == 0) ? r0
                       : (i_col == 1) ? r1
                       : (i_col == 2) ? r2 : r3;
        if (i_col < 4) atomicAdd(&psum_lds[gidx[m] * OUT_NODE + o], rv);
      }
    }
    p ^= 1;
  }

  __syncthreads();
  const float4* ps4 = reinterpret_cast<const float4*>(psum_lds);
  float4* pp4 = reinterpret_cast<float4*>(
      part + (size_t)blockIdx.x * (N_GRAPHS * OUT_NODE));
  for (int t = tid; t < (N_GRAPHS * OUT_NODE) / 4; t += 256) pp4[t] = ps4[t];
}

// ---------------------------------------------------------------------------
// Kernel 3b: reduce 1024 block partials -> psum. 16 slices x 2560 idx,
// consecutive threads = consecutive idx (coalesced).
// ---------------------------------------------------------------------------
__global__ __launch_bounds__(256) void reduce_part(
    const float* __restrict__ part, float* __restrict__ psum) {
  const int j = blockIdx.x * 256 + threadIdx.x;  // 0..40959
  const int slice = j / (N_GRAPHS * OUT_NODE);
  const int idx = j % (N_GRAPHS * OUT_NODE);
  float s = 0.f;
#pragma unroll 4
  for (int r = 0; r < EDGE_GRID / 16; ++r)
    s += part[(size_t)(slice * (EDGE_GRID / 16) + r) * (N_GRAPHS * OUT_NODE) +
              idx];
  atomicAdd(&psum[idx], s);
}

// ---------------------------------------------------------------------------
// Kernel 4: psum[g] += sum_{n in g} (x[n]@root + bias); pcnt[g] += count.
// ---------------------------------------------------------------------------
__global__ __launch_bounds__(256) void node_kernel(
    const float* __restrict__ x, const float* __restrict__ rootg,
    const float* __restrict__ biasg, const int* __restrict__ batch,
    float* __restrict__ psum, float* __restrict__ pcnt) {
  __shared__ float roots[IN_NODE * OUT_NODE];
  __shared__ float biass[OUT_NODE];
  for (int t = threadIdx.x; t < IN_NODE * OUT_NODE; t += 256)
    roots[t] = rootg[t];
  if (threadIdx.x < OUT_NODE) biass[threadIdx.x] = biasg[threadIdx.x];
  __syncthreads();

  const int n = blockIdx.x * blockDim.x + threadIdx.x;
  const int lane = threadIdx.x & 63;
  const bool valid = n < N_NODES;

  float v[OUT_NODE];
  int g = -1;
  if (valid) {
    g = batch[n];
    const float4* xp = reinterpret_cast<const float4*>(&x[n * IN_NODE]);
    const float4 a0 = xp[0], a1 = xp[1], a2 = xp[2], a3 = xp[3];
    const float xf[IN_NODE] = {a0.x, a0.y, a0.z, a0.w, a1.x, a1.y, a1.z, a1.w,
                               a2.x, a2.y, a2.z, a2.w, a3.x, a3.y, a3.z, a3.w};
#pragma unroll
    for (int o = 0; o < OUT_NODE; ++o) {
      float s = biass[o];
#pragma unroll
      for (int i = 0; i < IN_NODE; ++i) s += xf[i] * roots[i * OUT_NODE + o];
      v[o] = s;
    }
  } else {
#pragma unroll
    for (int o = 0; o < OUT_NODE; ++o) v[o] = 0.f;
  }

  const int g0 = __builtin_amdgcn_readfirstlane(g);
  const bool uni = (__ballot(valid && (g == g0)) == 0xFFFFFFFFFFFFFFFFull);

  if (uni) {
#pragma unroll
    for (int o = 0; o < OUT_NODE; ++o) {
      float s = v[o];
      ROW_SUM16(s);
      s += __shfl_xor(s, 16, 64);
      s += __shfl_xor(s, 32, 64);
      v[o] = s;
    }
    if (lane == 0) {
#pragma unroll
      for (int o = 0; o < OUT_NODE; ++o)
        atomicAdd(&psum[g0 * OUT_NODE + o], v[o]);
      atomicAdd(&pcnt[g0], 64.f);
    }
  } else if (valid) {
#pragma unroll
    for (int o = 0; o < OUT_NODE; ++o) atomicAdd(&psum[g * OUT_NODE + o], v[o]);
    atomicAdd(&pcnt[g], 1.f);
  }
}

// ---------------------------------------------------------------------------
// Kernel 5: per-graph actor MLP. One block per graph.
// ---------------------------------------------------------------------------
__global__ __launch_bounds__(256) void actor_kernel(
    const float* __restrict__ psum, const float* __restrict__ pcnt,
    const float* __restrict__ A1, const float* __restrict__ ab1,
    const float* __restrict__ A2, const float* __restrict__ ab2,
    float* __restrict__ out) {
  __shared__ float pooled[OUT_NODE];
  __shared__ float a_s[HA];
  __shared__ float red[16][N_ACT];

  const int g = blockIdx.x;
  const int t = threadIdx.x;
  if (t < OUT_NODE) {
    const float c = fmaxf(pcnt[g], 1.f);
    pooled[t] = psum[g * OUT_NODE + t] / c;
  }
  __syncthreads();
  {
    float v = ab1[t];
#pragma unroll
    for (int k = 0; k < OUT_NODE; ++k) v += pooled[k] * A1[k * HA + t];
    a_s[t] = fmaxf(v, 0.f);
  }
  __syncthreads();
  {
    const int j = t & 15, seg = t >> 4;
    float v = 0.f;
#pragma unroll
    for (int kk = 0; kk < 16; ++kk) {
      const int k = seg * 16 + kk;
      v += a_s[k] * A2[k * N_ACT + j];
    }
    red[seg][j] = v;
  }
  __syncthreads();
  if (t < N_ACT) {
    float s = ab2[t];
#pragma unroll
    for (int seg = 0; seg < 16; ++seg) s += red[seg][t];
    out[g * N_ACT + t] = s;
  }
}

// ---------------------------------------------------------------------------
extern "C" void kernel_launch(void* const* d_in, const int* in_sizes, int n_in,
                              void* d_out, int out_size, void* d_ws,
                              size_t ws_size, hipStream_t stream) {
  const float* x     = (const float*)d_in[0];
  const int*   ei    = (const int*)d_in[1];
  const float* ea    = (const float*)d_in[2];
  const int*   batch = (const int*)d_in[3];
  const float* W1    = (const float*)d_in[4];
  const float* b1    = (const float*)d_in[5];
  const float* gamma = (const float*)d_in[6];
  const float* beta  = (const float*)d_in[7];
  const float* W2    = (const float*)d_in[8];
  const float* b2    = (const float*)d_in[9];
  const float* root  = (const float*)d_in[10];
  const float* bias  = (const float*)d_in[11];
  const float* A1    = (const float*)d_in[12];
  const float* ab1   = (const float*)d_in[13];
  const float* A2    = (const float*)d_in[14];
  const float* ab2   = (const float*)d_in[15];
  float* out = (float*)d_out;

  float* ws = (float*)d_ws;
  float* hdr   = ws;                          // [0:10) colsum, [16:71) gram
  float* scale = ws + 128;                    // 64
  float* c1    = ws + 192;                    // 64
  float* psum  = ws + 256;                    // 2560
  float* pcnt  = psum + N_GRAPHS * OUT_NODE;  // 128
  float* partb = pcnt + N_GRAPHS;             // EDGE_GRID*2560 = 10.49 MB

  const size_t zero_bytes =
      (256 + N_GRAPHS * OUT_NODE + N_GRAPHS) * sizeof(float);
  hipMemsetAsync(d_ws, 0, zero_bytes, stream);

  bn_stats<<<64, 256, 0, stream>>>(ea, hdr);
  bn_finalize<<<1, 64, 0, stream>>>(hdr, W1, b1, gamma, beta, scale, c1);
  edge_main<<<EDGE_GRID, 256, 0, stream>>>(x, ei, ea, W1, W2, b2, scale, c1,
                                           batch, partb);
  reduce_part<<<160, 256, 0, stream>>>(partb, psum);
  node_kernel<<<(N_NODES + 255) / 256, 256, 0, stream>>>(x, root, bias, batch,
                                                         psum, pcnt);
  actor_kernel<<<N_GRAPHS, 256, 0, stream>>>(psum, pcnt, A1, ab1, A2, ab2, out);
}

// Round 6
// 146.265 us; speedup vs baseline: 7.1615x; 1.6244x over previous
//
#include <hip/hip_runtime.h>

#define N_NODES   50000
#define N_EDGES   400000
#define IN_NODE   16
#define OUT_NODE  20
#define IN_EDGE   10
#define HE        64
#define HA        256
#define N_ACT     16
#define N_GRAPHS  128
#define BN_EPS    1e-5f
#define HNST      68          // LDS row stride (shorts) for hnT/xT
#define SPLIT     4           // S-kernel blocks per graph

typedef __attribute__((ext_vector_type(8))) short short8v;
typedef __attribute__((ext_vector_type(4))) float f32x4;

__device__ __forceinline__ unsigned short f2bf(float f) {
  unsigned u = __float_as_uint(f);
  u += 0x7fffu + ((u >> 16) & 1u);  // RNE
  return (unsigned short)(u >> 16);
}
__device__ __forceinline__ float bf2f(short s) {
  return __uint_as_float(((unsigned)(unsigned short)s) << 16);
}

#define DPP_ROR_ADD(v, CTRL)                                                  \
  ((v) + __int_as_float(__builtin_amdgcn_update_dpp(                          \
             0, __float_as_int(v), (CTRL), 0xF, 0xF, true)))
#define ROW_SUM16(v)                                                          \
  do {                                                                        \
    v = DPP_ROR_ADD(v, 0x128);                                                \
    v = DPP_ROR_ADD(v, 0x124);                                                \
    v = DPP_ROR_ADD(v, 0x122);                                                \
    v = DPP_ROR_ADD(v, 0x121);                                                \
  } while (0)

// ---------------------------------------------------------------------------
// Kernel 1: BN stats via Gram trick (colsum + 10x10 Gram of ea).
// hdr: [0:10) colsum, [16:71) packed upper-tri gram.
// ---------------------------------------------------------------------------
__global__ __launch_bounds__(256) void bn_stats(const float* __restrict__ ea,
                                                float* __restrict__ hdr) {
  float cs[10];
  float gm[55];
#pragma unroll
  for (int a = 0; a < 10; ++a) cs[a] = 0.f;
#pragma unroll
  for (int u = 0; u < 55; ++u) gm[u] = 0.f;

  for (int e = blockIdx.x * 256 + threadIdx.x; e < N_EDGES; e += 256 * 256) {
    const float2* rp = reinterpret_cast<const float2*>(ea + (size_t)e * 10);
    float f[10];
#pragma unroll
    for (int p = 0; p < 5; ++p) {
      const float2 t = rp[p];
      f[2 * p] = t.x;
      f[2 * p + 1] = t.y;
    }
#pragma unroll
    for (int a = 0; a < 10; ++a) cs[a] += f[a];
    int idx = 0;
#pragma unroll
    for (int a = 0; a < 10; ++a)
#pragma unroll
      for (int b = a; b < 10; ++b) {
        gm[idx] = fmaf(f[a], f[b], gm[idx]);
        ++idx;
      }
  }

#pragma unroll
  for (int v = 0; v < 10; ++v)
#pragma unroll
    for (int off = 1; off < 64; off <<= 1) cs[v] += __shfl_xor(cs[v], off, 64);
#pragma unroll
  for (int u = 0; u < 55; ++u)
#pragma unroll
    for (int off = 1; off < 64; off <<= 1) gm[u] += __shfl_xor(gm[u], off, 64);

  __shared__ float red[4][72];
  const int lane = threadIdx.x & 63;
  const int w = threadIdx.x >> 6;
  if (lane == 0) {
#pragma unroll
    for (int v = 0; v < 10; ++v) red[w][v] = cs[v];
#pragma unroll
    for (int u = 0; u < 55; ++u) red[w][10 + u] = gm[u];
  }
  __syncthreads();
  if (threadIdx.x < 65) {
    const int t = threadIdx.x;
    const float s = red[0][t] + red[1][t] + red[2][t] + red[3][t];
    const int dst = (t < 10) ? t : 6 + t;
    atomicAdd(&hdr[dst], s);
  }
}

// ---------------------------------------------------------------------------
// Kernel 2: finalize -> per-channel (scale, c1), hn = relu(scale*u + c1),
// u = ea@W1 (b1 folded into c1).
// ---------------------------------------------------------------------------
__global__ void bn_finalize(const float* __restrict__ hdr,
                            const float* __restrict__ W1,
                            const float* __restrict__ b1,
                            const float* __restrict__ gamma,
                            const float* __restrict__ beta,
                            float* __restrict__ scale,
                            float* __restrict__ c1out) {
  const int c = threadIdx.x;
  if (c >= HE) return;
  float wc[10];
#pragma unroll
  for (int k = 0; k < 10; ++k) wc[k] = W1[k * HE + c];
  float su = 0.f;
#pragma unroll
  for (int k = 0; k < 10; ++k) su = fmaf(hdr[k], wc[k], su);
  float q = 0.f;
  int idx = 0;
#pragma unroll
  for (int a = 0; a < 10; ++a) {
    q = fmaf(hdr[16 + idx], wc[a] * wc[a], q);
    ++idx;
#pragma unroll
    for (int b = a + 1; b < 10; ++b) {
      q = fmaf(2.f * hdr[16 + idx], wc[a] * wc[b], q);
      ++idx;
    }
  }
  const float b1c = b1[c];
  const float invE = 1.f / (float)N_EDGES;
  const float mu = su * invE + b1c;
  const float Eh2 = (q + 2.f * b1c * su) * invE + b1c * b1c;
  const float var = Eh2 - mu * mu;
  const float sc = gamma[c] * rsqrtf(var + BN_EPS);
  scale[c] = sc;
  c1out[c] = sc * (b1c - mu) + beta[c];
}

// ---------------------------------------------------------------------------
// Kernel 3: per-edge graph id + histogram. ge[e] = batch[dst[e]].
// ---------------------------------------------------------------------------
__global__ __launch_bounds__(256) void hist_g(const int* __restrict__ ei,
                                              const int* __restrict__ batch,
                                              int* __restrict__ ge,
                                              int* __restrict__ hist) {
  __shared__ int lh[N_GRAPHS];
  for (int t = threadIdx.x; t < N_GRAPHS; t += 256) lh[t] = 0;
  __syncthreads();
  for (int e = blockIdx.x * 256 + threadIdx.x; e < N_EDGES; e += 256 * 256) {
    const int g = batch[ei[N_EDGES + e]];
    ge[e] = g;
    atomicAdd(&lh[g], 1);
  }
  __syncthreads();
  if (threadIdx.x < N_GRAPHS) atomicAdd(&hist[threadIdx.x], lh[threadIdx.x]);
}

// ---------------------------------------------------------------------------
// Kernel 4: exclusive scan of hist -> bstart[129]; cursor init.
// ---------------------------------------------------------------------------
__global__ void scan_k(const int* __restrict__ hist, int* __restrict__ bstart,
                       int* __restrict__ cursor) {
  __shared__ int v[N_GRAPHS];
  const int t = threadIdx.x;  // block of 128
  const int h = hist[t];
  v[t] = h;
  __syncthreads();
  for (int off = 1; off < N_GRAPHS; off <<= 1) {
    int y = 0;
    if (t >= off) y = v[t - off];
    __syncthreads();
    v[t] += y;
    __syncthreads();
  }
  const int excl = v[t] - h;
  bstart[t] = excl;
  cursor[t] = excl;
  if (t == N_GRAPHS - 1) bstart[N_GRAPHS] = v[t];
}

// ---------------------------------------------------------------------------
// Kernel 5: scatter edge ids into graph buckets (non-stable counting sort).
// Per-block LDS ranks, one global atomic per (block, graph).
// ---------------------------------------------------------------------------
__global__ __launch_bounds__(256) void scatter_k(const int* __restrict__ ge,
                                                 int* __restrict__ cursor,
                                                 int* __restrict__ perm) {
  __shared__ int lh[N_GRAPHS];
  __shared__ int gb[N_GRAPHS];
  for (int t = threadIdx.x; t < N_GRAPHS; t += 256) lh[t] = 0;
  __syncthreads();
  int gj[7], lr[7], ej[7];
#pragma unroll
  for (int j = 0; j < 7; ++j) {
    const int e = blockIdx.x * 256 + threadIdx.x + j * 65536;
    ej[j] = e;
    gj[j] = -1;
    lr[j] = 0;
    if (e < N_EDGES) {
      const int g = ge[e];
      gj[j] = g;
      lr[j] = atomicAdd(&lh[g], 1);
    }
  }
  __syncthreads();
  if (threadIdx.x < N_GRAPHS && lh[threadIdx.x] > 0)
    gb[threadIdx.x] = atomicAdd(&cursor[threadIdx.x], lh[threadIdx.x]);
  __syncthreads();
#pragma unroll
  for (int j = 0; j < 7; ++j)
    if (gj[j] >= 0) perm[gb[gj[j]] + lr[j]] = ej[j];
}

// ---------------------------------------------------------------------------
// Kernel 6: S accumulation. 4 blocks per graph, each owns an edge range.
//  S[c,i] += hn[e,c]*x[src_e,i]  via MFMA: A = hnT[c][e] (bf16, LDS),
//  B = xT[i... B[k=e][i] from xT[i][e] (bf16, LDS). Wave w = c-tile w.
//  Also XS[i] = sum_e x[e,i] (wave 0, from B-frags). Partials to ws.
// ---------------------------------------------------------------------------
__global__ __launch_bounds__(256) void s_kernel(
    const float* __restrict__ x, const int* __restrict__ ei,
    const float* __restrict__ ea, const float* __restrict__ W1g,
    const float* __restrict__ scale, const float* __restrict__ c1g,
    const int* __restrict__ perm, const int* __restrict__ bstart,
    float* __restrict__ Spart, float* __restrict__ XSpart) {
  __shared__ short hnT[2][64 * HNST];  // [c][e]
  __shared__ short xT[2][16 * HNST];   // [i][e]

  const int tid = threadIdx.x;
  const int lane = tid & 63;
  const int w = tid >> 6;
  const int i_col = lane & 15;
  const int kq = lane >> 4;

  const int g = blockIdx.x / SPLIT;
  const int pp = blockIdx.x & (SPLIT - 1);
  const int gs = bstart[g], geE = bstart[g + 1];
  const int cnt = geE - gs;
  const int p0 = gs + (cnt * pp) / SPLIT;
  const int p1 = gs + (cnt * (pp + 1)) / SPLIT;

  // W1 B-frags (bf16, K pad 10->32) + per-lane affine
  short8v w1f[4];
  float scv[4], c1v[4];
#pragma unroll
  for (int nt = 0; nt < 4; ++nt) {
    short8v v;
#pragma unroll
    for (int j = 0; j < 8; ++j) {
      const int k = kq * 8 + j;
      const float f = (k < IN_EDGE) ? W1g[k * HE + nt * 16 + i_col] : 0.f;
      v[j] = (short)f2bf(f);
    }
    w1f[nt] = v;
    scv[nt] = scale[nt * 16 + i_col];
    c1v[nt] = c1g[nt * 16 + i_col];
  }

  f32x4 acc = {0.f, 0.f, 0.f, 0.f};
  float xs = 0.f;

  int p = 0;
  for (int base = p0; base < p1; base += 64) {
    // ---- produce hn (wave w: edges base+w*16 .. +15) ----
    {
      const int er = base + w * 16 + i_col;
      const bool val = er < p1;
      const int pe = val ? perm[er] : 0;
      const float* row = ea + (size_t)pe * IN_EDGE;
      float af[8];
#pragma unroll
      for (int j = 0; j < 8; ++j) af[j] = 0.f;
      if (val) {
#pragma unroll
        for (int pr = 0; pr < 4; ++pr) {
          const int k = kq * 8 + pr * 2;
          if (k < IN_EDGE) {
            const float2 t2 = *reinterpret_cast<const float2*>(row + k);
            af[pr * 2] = t2.x;
            af[pr * 2 + 1] = t2.y;
          }
        }
      }
      short8v ae;
#pragma unroll
      for (int j = 0; j < 8; ++j) ae[j] = (short)f2bf(af[j]);

      const f32x4 zero4 = {0.f, 0.f, 0.f, 0.f};
#pragma unroll
      for (int nt = 0; nt < 4; ++nt) {
        const f32x4 hv = __builtin_amdgcn_mfma_f32_16x16x32_bf16(
            ae, w1f[nt], zero4, 0, 0, 0);
        short4 sv;
        {
          const int e0 = base + w * 16 + kq * 4;
          const float h0 = (e0 + 0 < p1) ? fmaxf(fmaf(hv[0], scv[nt], c1v[nt]), 0.f) : 0.f;
          const float h1 = (e0 + 1 < p1) ? fmaxf(fmaf(hv[1], scv[nt], c1v[nt]), 0.f) : 0.f;
          const float h2 = (e0 + 2 < p1) ? fmaxf(fmaf(hv[2], scv[nt], c1v[nt]), 0.f) : 0.f;
          const float h3 = (e0 + 3 < p1) ? fmaxf(fmaf(hv[3], scv[nt], c1v[nt]), 0.f) : 0.f;
          sv.x = (short)f2bf(h0);
          sv.y = (short)f2bf(h1);
          sv.z = (short)f2bf(h2);
          sv.w = (short)f2bf(h3);
        }
        *reinterpret_cast<short4*>(
            &hnT[p][(nt * 16 + i_col) * HNST + w * 16 + kq * 4]) = sv;
      }
    }
    // ---- stage xT (thread tid: edge tid>>2, quarter-row tid&3) ----
    {
      const int et = tid >> 2, iq = tid & 3;
      const int er = base + et;
      float4 xv = {0.f, 0.f, 0.f, 0.f};
      if (er < p1) {
        const int pe = perm[er];
        const int s = ei[pe];
        xv = *reinterpret_cast<const float4*>(&x[(size_t)s * IN_NODE + iq * 4]);
      }
      xT[p][(iq * 4 + 0) * HNST + et] = (short)f2bf(xv.x);
      xT[p][(iq * 4 + 1) * HNST + et] = (short)f2bf(xv.y);
      xT[p][(iq * 4 + 2) * HNST + et] = (short)f2bf(xv.z);
      xT[p][(iq * 4 + 3) * HNST + et] = (short)f2bf(xv.w);
    }
    __syncthreads();
    // ---- consume: K = 64 edges, wave w's c-tile ----
#pragma unroll
    for (int ks = 0; ks < 2; ++ks) {
      const short8v a = *reinterpret_cast<const short8v*>(
          &hnT[p][(w * 16 + i_col) * HNST + ks * 32 + kq * 8]);
      const short8v b = *reinterpret_cast<const short8v*>(
          &xT[p][i_col * HNST + ks * 32 + kq * 8]);
      acc = __builtin_amdgcn_mfma_f32_16x16x32_bf16(a, b, acc, 0, 0, 0);
      if (w == 0) {
#pragma unroll
        for (int j = 0; j < 8; ++j) xs += bf2f(b[j]);
      }
    }
    p ^= 1;
  }

  // write partials: lane holds S[c = w*16 + kq*4 + r][i = i_col]
#pragma unroll
  for (int r = 0; r < 4; ++r)
    Spart[(size_t)blockIdx.x * 1024 + (w * 16 + kq * 4 + r) * 16 + i_col] =
        acc[r];
  if (w == 0) {
    xs += __shfl_xor(xs, 16, 64);
    xs += __shfl_xor(xs, 32, 64);
    if (kq == 0) XSpart[blockIdx.x * 16 + i_col] = xs;
  }
}

// ---------------------------------------------------------------------------
// Kernel 7: psum[g] += sum_{n in g} (x[n]@root + bias); pcnt[g] += count.
// ---------------------------------------------------------------------------
__global__ __launch_bounds__(256) void node_kernel(
    const float* __restrict__ x, const float* __restrict__ rootg,
    const float* __restrict__ biasg, const int* __restrict__ batch,
    float* __restrict__ psum, float* __restrict__ pcnt) {
  __shared__ float roots[IN_NODE * OUT_NODE];
  __shared__ float biass[OUT_NODE];
  for (int t = threadIdx.x; t < IN_NODE * OUT_NODE; t += 256)
    roots[t] = rootg[t];
  if (threadIdx.x < OUT_NODE) biass[threadIdx.x] = biasg[threadIdx.x];
  __syncthreads();

  const int n = blockIdx.x * blockDim.x + threadIdx.x;
  const int lane = threadIdx.x & 63;
  const bool valid = n < N_NODES;

  float v[OUT_NODE];
  int g = -1;
  if (valid) {
    g = batch[n];
    const float4* xp = reinterpret_cast<const float4*>(&x[n * IN_NODE]);
    const float4 a0 = xp[0], a1 = xp[1], a2 = xp[2], a3 = xp[3];
    const float xf[IN_NODE] = {a0.x, a0.y, a0.z, a0.w, a1.x, a1.y, a1.z, a1.w,
                               a2.x, a2.y, a2.z, a2.w, a3.x, a3.y, a3.z, a3.w};
#pragma unroll
    for (int o = 0; o < OUT_NODE; ++o) {
      float s = biass[o];
#pragma unroll
      for (int i = 0; i < IN_NODE; ++i) s += xf[i] * roots[i * OUT_NODE + o];
      v[o] = s;
    }
  } else {
#pragma unroll
    for (int o = 0; o < OUT_NODE; ++o) v[o] = 0.f;
  }

  const int g0 = __builtin_amdgcn_readfirstlane(g);
  const bool uni = (__ballot(valid && (g == g0)) == 0xFFFFFFFFFFFFFFFFull);

  if (uni) {
#pragma unroll
    for (int o = 0; o < OUT_NODE; ++o) {
      float s = v[o];
      ROW_SUM16(s);
      s += __shfl_xor(s, 16, 64);
      s += __shfl_xor(s, 32, 64);
      v[o] = s;
    }
    if (lane == 0) {
#pragma unroll
      for (int o = 0; o < OUT_NODE; ++o)
        atomicAdd(&psum[g0 * OUT_NODE + o], v[o]);
      atomicAdd(&pcnt[g0], 64.f);
    }
  } else if (valid) {
#pragma unroll
    for (int o = 0; o < OUT_NODE; ++o) atomicAdd(&psum[g * OUT_NODE + o], v[o]);
    atomicAdd(&pcnt[g], 1.f);
  }
}

// ---------------------------------------------------------------------------
// Kernel 8: fuse. Per graph: sum S partials; pooled[o] = (S.W2 + XS.b2 +
// psum_root)/cnt; actor MLP -> out.
// ---------------------------------------------------------------------------
__global__ __launch_bounds__(256) void fuse_k(
    const float* __restrict__ Spart, const float* __restrict__ XSpart,
    const float* __restrict__ W2g, const float* __restrict__ b2g,
    const float* __restrict__ psum, const float* __restrict__ pcnt,
    const float* __restrict__ A1, const float* __restrict__ ab1,
    const float* __restrict__ A2, const float* __restrict__ ab2,
    float* __restrict__ out) {
  __shared__ float S_l[1024];
  __shared__ float xs_l[16];
  __shared__ float pooled[OUT_NODE];
  __shared__ float a_s[HA];
  __shared__ float red[16][N_ACT];

  const int g = blockIdx.x;
  const int tid = threadIdx.x, lane = tid & 63, w = tid >> 6;

  for (int t = tid; t < 1024; t += 256) {
    float s = 0.f;
#pragma unroll
    for (int q = 0; q < SPLIT; ++q)
      s += Spart[(size_t)(SPLIT * g + q) * 1024 + t];
    S_l[t] = s;
  }
  if (tid < 16) {
    float s = 0.f;
#pragma unroll
    for (int q = 0; q < SPLIT; ++q) s += XSpart[(SPLIT * g + q) * 16 + tid];
    xs_l[tid] = s;
  }
  __syncthreads();

#pragma unroll
  for (int oi = 0; oi < 5; ++oi) {
    const int o = w * 5 + oi;
    float s = 0.f;
#pragma unroll
    for (int j = 0; j < 16; ++j) {
      const int u = lane + 64 * j;
      const int c = u >> 4, i = u & 15;
      s = fmaf(S_l[u], W2g[c * (IN_NODE * OUT_NODE) + i * OUT_NODE + o], s);
    }
    if (lane < 16) s = fmaf(xs_l[lane], b2g[lane * OUT_NODE + o], s);
    ROW_SUM16(s);
    s += __shfl_xor(s, 16, 64);
    s += __shfl_xor(s, 32, 64);
    if (lane == 0) pooled[o] = s + psum[g * OUT_NODE + o];
  }
  __syncthreads();

  const float invc = 1.f / fmaxf(pcnt[g], 1.f);
  {
    float v = ab1[tid];
#pragma unroll
    for (int k = 0; k < OUT_NODE; ++k)
      v = fmaf(pooled[k] * invc, A1[k * HA + tid], v);
    a_s[tid] = fmaxf(v, 0.f);
  }
  __syncthreads();
  {
    const int j = tid & 15, seg = tid >> 4;
    float v = 0.f;
#pragma unroll
    for (int kk = 0; kk < 16; ++kk) {
      const int k = seg * 16 + kk;
      v += a_s[k] * A2[k * N_ACT + j];
    }
    red[seg][j] = v;
  }
  __syncthreads();
  if (tid < N_ACT) {
    float s = ab2[tid];
#pragma unroll
    for (int seg = 0; seg < 16; ++seg) s += red[seg][tid];
    out[g * N_ACT + tid] = s;
  }
}

// ---------------------------------------------------------------------------
extern "C" void kernel_launch(void* const* d_in, const int* in_sizes, int n_in,
                              void* d_out, int out_size, void* d_ws,
                              size_t ws_size, hipStream_t stream) {
  const float* x     = (const float*)d_in[0];
  const int*   ei    = (const int*)d_in[1];
  const float* ea    = (const float*)d_in[2];
  const int*   batch = (const int*)d_in[3];
  const float* W1    = (const float*)d_in[4];
  const float* b1    = (const float*)d_in[5];
  const float* gamma = (const float*)d_in[6];
  const float* beta  = (const float*)d_in[7];
  const float* W2    = (const float*)d_in[8];
  const float* b2    = (const float*)d_in[9];
  const float* root  = (const float*)d_in[10];
  const float* bias  = (const float*)d_in[11];
  const float* A1    = (const float*)d_in[12];
  const float* ab1   = (const float*)d_in[13];
  const float* A2    = (const float*)d_in[14];
  const float* ab2   = (const float*)d_in[15];
  float* out = (float*)d_out;

  float* ws = (float*)d_ws;
  int*   iw = (int*)d_ws;
  // float-word offsets
  float* hdr    = ws;                 // [0:128)
  float* scale  = ws + 128;           // [128:192)
  float* c1     = ws + 192;           // [192:256)
  float* psum   = ws + 256;           // [256:2816)
  float* pcnt   = ws + 2816;          // [2816:2944)
  int*   hist   = iw + 2944;          // [2944:3072) int
  // --- zeroed through 3072 words ---
  int*   bstart = iw + 3072;          // 129 ints (+pad)
  int*   cursor = iw + 3208;          // 128 ints
  int*   ge     = iw + 3336;          // 400000 ints
  int*   perm   = iw + 403336;        // 400000 ints
  float* Spart  = ws + 803336;        // 512*1024
  float* XSpart = ws + 1327624;       // 512*16

  hipMemsetAsync(d_ws, 0, 3072 * sizeof(float), stream);

  bn_stats<<<256, 256, 0, stream>>>(ea, hdr);
  bn_finalize<<<1, 64, 0, stream>>>(hdr, W1, b1, gamma, beta, scale, c1);
  hist_g<<<256, 256, 0, stream>>>(ei, batch, ge, hist);
  scan_k<<<1, 128, 0, stream>>>(hist, bstart, cursor);
  scatter_k<<<256, 256, 0, stream>>>(ge, cursor, perm);
  s_kernel<<<N_GRAPHS * SPLIT, 256, 0, stream>>>(x, ei, ea, W1, scale, c1,
                                                 perm, bstart, Spart, XSpart);
  node_kernel<<<(N_NODES + 255) / 256, 256, 0, stream>>>(x, root, bias, batch,
                                                         psum, pcnt);
  fuse_k<<<N_GRAPHS, 256, 0, stream>>>(Spart, XSpart, W2, b2, psum, pcnt, A1,
                                       ab1, A2, ab2, out);
}

// Round 7
// 104.384 us; speedup vs baseline: 10.0349x; 1.4012x over previous
//
#include <hip/hip_runtime.h>

#define N_NODES   50000
#define N_EDGES   400000
#define IN_NODE   16
#define OUT_NODE  20
#define IN_EDGE   10
#define HE        64
#define HA        256
#define N_ACT     16
#define N_GRAPHS  128
#define BN_EPS    1e-5f
#define HNST      68          // LDS row stride (shorts) for hnT/xT
#define SPLIT     4           // S-kernel blocks per graph

typedef __attribute__((ext_vector_type(8))) short short8v;
typedef __attribute__((ext_vector_type(4))) float f32x4;

__device__ __forceinline__ unsigned short f2bf(float f) {
  unsigned u = __float_as_uint(f);
  u += 0x7fffu + ((u >> 16) & 1u);  // RNE
  return (unsigned short)(u >> 16);
}
__device__ __forceinline__ float bf2f(short s) {
  return __uint_as_float(((unsigned)(unsigned short)s) << 16);
}

#define DPP_ROR_ADD(v, CTRL)                                                  \
  ((v) + __int_as_float(__builtin_amdgcn_update_dpp(                          \
             0, __float_as_int(v), (CTRL), 0xF, 0xF, true)))
#define ROW_SUM16(v)                                                          \
  do {                                                                        \
    v = DPP_ROR_ADD(v, 0x128);                                                \
    v = DPP_ROR_ADD(v, 0x124);                                                \
    v = DPP_ROR_ADD(v, 0x122);                                                \
    v = DPP_ROR_ADD(v, 0x121);                                                \
  } while (0)

// ---------------------------------------------------------------------------
// Kernel 1: BN stats via Gram trick (colsum + 10x10 Gram of ea).
// hdr: [0:10) colsum, [16:71) packed upper-tri gram.
// ---------------------------------------------------------------------------
__global__ __launch_bounds__(256) void bn_stats(const float* __restrict__ ea,
                                                float* __restrict__ hdr) {
  float cs[10];
  float gm[55];
#pragma unroll
  for (int a = 0; a < 10; ++a) cs[a] = 0.f;
#pragma unroll
  for (int u = 0; u < 55; ++u) gm[u] = 0.f;

  for (int e = blockIdx.x * 256 + threadIdx.x; e < N_EDGES; e += 256 * 256) {
    const float2* rp = reinterpret_cast<const float2*>(ea + (size_t)e * 10);
    float f[10];
#pragma unroll
    for (int p = 0; p < 5; ++p) {
      const float2 t = rp[p];
      f[2 * p] = t.x;
      f[2 * p + 1] = t.y;
    }
#pragma unroll
    for (int a = 0; a < 10; ++a) cs[a] += f[a];
    int idx = 0;
#pragma unroll
    for (int a = 0; a < 10; ++a)
#pragma unroll
      for (int b = a; b < 10; ++b) {
        gm[idx] = fmaf(f[a], f[b], gm[idx]);
        ++idx;
      }
  }

#pragma unroll
  for (int v = 0; v < 10; ++v)
#pragma unroll
    for (int off = 1; off < 64; off <<= 1) cs[v] += __shfl_xor(cs[v], off, 64);
#pragma unroll
  for (int u = 0; u < 55; ++u)
#pragma unroll
    for (int off = 1; off < 64; off <<= 1) gm[u] += __shfl_xor(gm[u], off, 64);

  __shared__ float red[4][72];
  const int lane = threadIdx.x & 63;
  const int w = threadIdx.x >> 6;
  if (lane == 0) {
#pragma unroll
    for (int v = 0; v < 10; ++v) red[w][v] = cs[v];
#pragma unroll
    for (int u = 0; u < 55; ++u) red[w][10 + u] = gm[u];
  }
  __syncthreads();
  if (threadIdx.x < 65) {
    const int t = threadIdx.x;
    const float s = red[0][t] + red[1][t] + red[2][t] + red[3][t];
    const int dst = (t < 10) ? t : 6 + t;
    atomicAdd(&hdr[dst], s);
  }
}

// ---------------------------------------------------------------------------
// Kernel 2: finalize -> per-channel (scale, c1), hn = relu(scale*u + c1),
// u = ea@W1 (b1 folded into c1).
// ---------------------------------------------------------------------------
__global__ void bn_finalize(const float* __restrict__ hdr,
                            const float* __restrict__ W1,
                            const float* __restrict__ b1,
                            const float* __restrict__ gamma,
                            const float* __restrict__ beta,
                            float* __restrict__ scale,
                            float* __restrict__ c1out) {
  const int c = threadIdx.x;
  if (c >= HE) return;
  float wc[10];
#pragma unroll
  for (int k = 0; k < 10; ++k) wc[k] = W1[k * HE + c];
  float su = 0.f;
#pragma unroll
  for (int k = 0; k < 10; ++k) su = fmaf(hdr[k], wc[k], su);
  float q = 0.f;
  int idx = 0;
#pragma unroll
  for (int a = 0; a < 10; ++a) {
    q = fmaf(hdr[16 + idx], wc[a] * wc[a], q);
    ++idx;
#pragma unroll
    for (int b = a + 1; b < 10; ++b) {
      q = fmaf(2.f * hdr[16 + idx], wc[a] * wc[b], q);
      ++idx;
    }
  }
  const float b1c = b1[c];
  const float invE = 1.f / (float)N_EDGES;
  const float mu = su * invE + b1c;
  const float Eh2 = (q + 2.f * b1c * su) * invE + b1c * b1c;
  const float var = Eh2 - mu * mu;
  const float sc = gamma[c] * rsqrtf(var + BN_EPS);
  scale[c] = sc;
  c1out[c] = sc * (b1c - mu) + beta[c];
}

// ---------------------------------------------------------------------------
// Kernel 3: per-edge graph id + histogram. ge[e] = batch[dst[e]].
// ---------------------------------------------------------------------------
__global__ __launch_bounds__(256) void hist_g(const int* __restrict__ ei,
                                              const int* __restrict__ batch,
                                              int* __restrict__ ge,
                                              int* __restrict__ hist) {
  __shared__ int lh[N_GRAPHS];
  for (int t = threadIdx.x; t < N_GRAPHS; t += 256) lh[t] = 0;
  __syncthreads();
  for (int e = blockIdx.x * 256 + threadIdx.x; e < N_EDGES; e += 256 * 256) {
    const int g = batch[ei[N_EDGES + e]];
    ge[e] = g;
    atomicAdd(&lh[g], 1);
  }
  __syncthreads();
  if (threadIdx.x < N_GRAPHS) atomicAdd(&hist[threadIdx.x], lh[threadIdx.x]);
}

// ---------------------------------------------------------------------------
// Kernel 4: exclusive scan of hist -> bstart[129]; cursor init.
// ---------------------------------------------------------------------------
__global__ void scan_k(const int* __restrict__ hist, int* __restrict__ bstart,
                       int* __restrict__ cursor) {
  __shared__ int v[N_GRAPHS];
  const int t = threadIdx.x;  // block of 128
  const int h = hist[t];
  v[t] = h;
  __syncthreads();
  for (int off = 1; off < N_GRAPHS; off <<= 1) {
    int y = 0;
    if (t >= off) y = v[t - off];
    __syncthreads();
    v[t] += y;
    __syncthreads();
  }
  const int excl = v[t] - h;
  bstart[t] = excl;
  cursor[t] = excl;
  if (t == N_GRAPHS - 1) bstart[N_GRAPHS] = v[t];
}

// ---------------------------------------------------------------------------
// Kernel 5: scatter edge ids into graph buckets (non-stable counting sort).
// ---------------------------------------------------------------------------
__global__ __launch_bounds__(256) void scatter_k(const int* __restrict__ ge,
                                                 int* __restrict__ cursor,
                                                 int* __restrict__ perm) {
  __shared__ int lh[N_GRAPHS];
  __shared__ int gb[N_GRAPHS];
  for (int t = threadIdx.x; t < N_GRAPHS; t += 256) lh[t] = 0;
  __syncthreads();
  int gj[7], lr[7], ej[7];
#pragma unroll
  for (int j = 0; j < 7; ++j) {
    const int e = blockIdx.x * 256 + threadIdx.x + j * 65536;
    ej[j] = e;
    gj[j] = -1;
    lr[j] = 0;
    if (e < N_EDGES) {
      const int g = ge[e];
      gj[j] = g;
      lr[j] = atomicAdd(&lh[g], 1);
    }
  }
  __syncthreads();
  if (threadIdx.x < N_GRAPHS && lh[threadIdx.x] > 0)
    gb[threadIdx.x] = atomicAdd(&cursor[threadIdx.x], lh[threadIdx.x]);
  __syncthreads();
#pragma unroll
  for (int j = 0; j < 7; ++j)
    if (gj[j] >= 0) perm[gb[gj[j]] + lr[j]] = ej[j];
}

// ---------------------------------------------------------------------------
// Kernel 6: S accumulation (unchanged from R6). 4 blocks per graph.
// ---------------------------------------------------------------------------
__global__ __launch_bounds__(256) void s_kernel(
    const float* __restrict__ x, const int* __restrict__ ei,
    const float* __restrict__ ea, const float* __restrict__ W1g,
    const float* __restrict__ scale, const float* __restrict__ c1g,
    const int* __restrict__ perm, const int* __restrict__ bstart,
    float* __restrict__ Spart, float* __restrict__ XSpart) {
  __shared__ short hnT[2][64 * HNST];  // [c][e]
  __shared__ short xT[2][16 * HNST];   // [i][e]

  const int tid = threadIdx.x;
  const int lane = tid & 63;
  const int w = tid >> 6;
  const int i_col = lane & 15;
  const int kq = lane >> 4;

  const int g = blockIdx.x / SPLIT;
  const int pp = blockIdx.x & (SPLIT - 1);
  const int gs = bstart[g], geE = bstart[g + 1];
  const int cnt = geE - gs;
  const int p0 = gs + (cnt * pp) / SPLIT;
  const int p1 = gs + (cnt * (pp + 1)) / SPLIT;

  short8v w1f[4];
  float scv[4], c1v[4];
#pragma unroll
  for (int nt = 0; nt < 4; ++nt) {
    short8v v;
#pragma unroll
    for (int j = 0; j < 8; ++j) {
      const int k = kq * 8 + j;
      const float f = (k < IN_EDGE) ? W1g[k * HE + nt * 16 + i_col] : 0.f;
      v[j] = (short)f2bf(f);
    }
    w1f[nt] = v;
    scv[nt] = scale[nt * 16 + i_col];
    c1v[nt] = c1g[nt * 16 + i_col];
  }

  f32x4 acc = {0.f, 0.f, 0.f, 0.f};
  float xs = 0.f;

  int p = 0;
  for (int base = p0; base < p1; base += 64) {
    {
      const int er = base + w * 16 + i_col;
      const bool val = er < p1;
      const int pe = val ? perm[er] : 0;
      const float* row = ea + (size_t)pe * IN_EDGE;
      float af[8];
#pragma unroll
      for (int j = 0; j < 8; ++j) af[j] = 0.f;
      if (val) {
#pragma unroll
        for (int pr = 0; pr < 4; ++pr) {
          const int k = kq * 8 + pr * 2;
          if (k < IN_EDGE) {
            const float2 t2 = *reinterpret_cast<const float2*>(row + k);
            af[pr * 2] = t2.x;
            af[pr * 2 + 1] = t2.y;
          }
        }
      }
      short8v ae;
#pragma unroll
      for (int j = 0; j < 8; ++j) ae[j] = (short)f2bf(af[j]);

      const f32x4 zero4 = {0.f, 0.f, 0.f, 0.f};
#pragma unroll
      for (int nt = 0; nt < 4; ++nt) {
        const f32x4 hv = __builtin_amdgcn_mfma_f32_16x16x32_bf16(
            ae, w1f[nt], zero4, 0, 0, 0);
        short4 sv;
        {
          const int e0 = base + w * 16 + kq * 4;
          const float h0 = (e0 + 0 < p1) ? fmaxf(fmaf(hv[0], scv[nt], c1v[nt]), 0.f) : 0.f;
          const float h1 = (e0 + 1 < p1) ? fmaxf(fmaf(hv[1], scv[nt], c1v[nt]), 0.f) : 0.f;
          const float h2 = (e0 + 2 < p1) ? fmaxf(fmaf(hv[2], scv[nt], c1v[nt]), 0.f) : 0.f;
          const float h3 = (e0 + 3 < p1) ? fmaxf(fmaf(hv[3], scv[nt], c1v[nt]), 0.f) : 0.f;
          sv.x = (short)f2bf(h0);
          sv.y = (short)f2bf(h1);
          sv.z = (short)f2bf(h2);
          sv.w = (short)f2bf(h3);
        }
        *reinterpret_cast<short4*>(
            &hnT[p][(nt * 16 + i_col) * HNST + w * 16 + kq * 4]) = sv;
      }
    }
    {
      const int et = tid >> 2, iq = tid & 3;
      const int er = base + et;
      float4 xv = {0.f, 0.f, 0.f, 0.f};
      if (er < p1) {
        const int pe = perm[er];
        const int s = ei[pe];
        xv = *reinterpret_cast<const float4*>(&x[(size_t)s * IN_NODE + iq * 4]);
      }
      xT[p][(iq * 4 + 0) * HNST + et] = (short)f2bf(xv.x);
      xT[p][(iq * 4 + 1) * HNST + et] = (short)f2bf(xv.y);
      xT[p][(iq * 4 + 2) * HNST + et] = (short)f2bf(xv.z);
      xT[p][(iq * 4 + 3) * HNST + et] = (short)f2bf(xv.w);
    }
    __syncthreads();
#pragma unroll
    for (int ks = 0; ks < 2; ++ks) {
      const short8v a = *reinterpret_cast<const short8v*>(
          &hnT[p][(w * 16 + i_col) * HNST + ks * 32 + kq * 8]);
      const short8v b = *reinterpret_cast<const short8v*>(
          &xT[p][i_col * HNST + ks * 32 + kq * 8]);
      acc = __builtin_amdgcn_mfma_f32_16x16x32_bf16(a, b, acc, 0, 0, 0);
      if (w == 0) {
#pragma unroll
        for (int j = 0; j < 8; ++j) xs += bf2f(b[j]);
      }
    }
    p ^= 1;
  }

#pragma unroll
  for (int r = 0; r < 4; ++r)
    Spart[(size_t)blockIdx.x * 1024 + (w * 16 + kq * 4 + r) * 16 + i_col] =
        acc[r];
  if (w == 0) {
    xs += __shfl_xor(xs, 16, 64);
    xs += __shfl_xor(xs, 32, 64);
    if (kq == 0) XSpart[blockIdx.x * 16 + i_col] = xs;
  }
}

// ---------------------------------------------------------------------------
// Kernel 7 (R7 rewrite): XN[g][i] = sum_{n in g} x[n][i]; cnt[g] += count.
// Root term pools: sum x@root = XN@root -> folded into fuse_k. LDS
// accumulation (wave-uniform fast path), nonzero-only global flush.
// Replaces the 52us atomic-chain node_kernel.
// ---------------------------------------------------------------------------
__global__ __launch_bounds__(256) void xsum_k(const float* __restrict__ x,
                                              const int* __restrict__ batch,
                                              float* __restrict__ XN,
                                              float* __restrict__ cnt) {
  __shared__ float xn_l[N_GRAPHS * IN_NODE];
  __shared__ float cnt_l[N_GRAPHS];
  const int tid = threadIdx.x;
  const int lane = tid & 63;
  for (int t = tid; t < N_GRAPHS * IN_NODE; t += 256) xn_l[t] = 0.f;
  if (tid < N_GRAPHS) cnt_l[tid] = 0.f;
  __syncthreads();

  const int n = blockIdx.x * 256 + tid;
  const bool valid = n < N_NODES;
  int g = -1;
  float xf[IN_NODE];
  if (valid) {
    g = batch[n];
    const float4* xp = reinterpret_cast<const float4*>(&x[(size_t)n * IN_NODE]);
    const float4 a0 = xp[0], a1 = xp[1], a2 = xp[2], a3 = xp[3];
    xf[0] = a0.x;  xf[1] = a0.y;  xf[2] = a0.z;  xf[3] = a0.w;
    xf[4] = a1.x;  xf[5] = a1.y;  xf[6] = a1.z;  xf[7] = a1.w;
    xf[8] = a2.x;  xf[9] = a2.y;  xf[10] = a2.z; xf[11] = a2.w;
    xf[12] = a3.x; xf[13] = a3.y; xf[14] = a3.z; xf[15] = a3.w;
  } else {
#pragma unroll
    for (int i = 0; i < IN_NODE; ++i) xf[i] = 0.f;
  }

  const int g0 = __builtin_amdgcn_readfirstlane(g);
  const bool uni = (__ballot(valid && (g == g0)) == 0xFFFFFFFFFFFFFFFFull);

  if (uni) {
#pragma unroll
    for (int i = 0; i < IN_NODE; ++i) {
      float s = xf[i];
      ROW_SUM16(s);
      s += __shfl_xor(s, 16, 64);
      s += __shfl_xor(s, 32, 64);
      xf[i] = s;
    }
    if (lane == 0) {
#pragma unroll
      for (int i = 0; i < IN_NODE; ++i) atomicAdd(&xn_l[g0 * IN_NODE + i], xf[i]);
      atomicAdd(&cnt_l[g0], 64.f);
    }
  } else if (valid) {
#pragma unroll
    for (int i = 0; i < IN_NODE; ++i) atomicAdd(&xn_l[g * IN_NODE + i], xf[i]);
    atomicAdd(&cnt_l[g], 1.f);
  }
  __syncthreads();

  // flush only touched entries (~2-3 graphs per block)
  if (tid < N_GRAPHS && cnt_l[tid] != 0.f) atomicAdd(&cnt[tid], cnt_l[tid]);
  for (int t = tid; t < N_GRAPHS * IN_NODE; t += 256) {
    const float v = xn_l[t];
    if (v != 0.f) atomicAdd(&XN[t], v);
  }
}

// ---------------------------------------------------------------------------
// Kernel 8: fuse. pooled[o] = (S.W2 + XS.b2 + XN@root)/cnt + bias; actor MLP.
// ---------------------------------------------------------------------------
__global__ __launch_bounds__(256) void fuse_k(
    const float* __restrict__ Spart, const float* __restrict__ XSpart,
    const float* __restrict__ W2g, const float* __restrict__ b2g,
    const float* __restrict__ XN, const float* __restrict__ cnt,
    const float* __restrict__ rootg, const float* __restrict__ biasg,
    const float* __restrict__ A1, const float* __restrict__ ab1,
    const float* __restrict__ A2, const float* __restrict__ ab2,
    float* __restrict__ out) {
  __shared__ float S_l[1024];
  __shared__ float xs_l[16];
  __shared__ float xn_f[16];
  __shared__ float pooled[OUT_NODE];
  __shared__ float a_s[HA];
  __shared__ float red[16][N_ACT];

  const int g = blockIdx.x;
  const int tid = threadIdx.x, lane = tid & 63, w = tid >> 6;

  for (int t = tid; t < 1024; t += 256) {
    float s = 0.f;
#pragma unroll
    for (int q = 0; q < SPLIT; ++q)
      s += Spart[(size_t)(SPLIT * g + q) * 1024 + t];
    S_l[t] = s;
  }
  if (tid < 16) {
    float s = 0.f;
#pragma unroll
    for (int q = 0; q < SPLIT; ++q) s += XSpart[(SPLIT * g + q) * 16 + tid];
    xs_l[tid] = s;
    xn_f[tid] = XN[g * IN_NODE + tid];
  }
  __syncthreads();

  const float invc = 1.f / fmaxf(cnt[g], 1.f);
#pragma unroll
  for (int oi = 0; oi < 5; ++oi) {
    const int o = w * 5 + oi;
    float s = 0.f;
#pragma unroll
    for (int j = 0; j < 16; ++j) {
      const int u = lane + 64 * j;
      const int c = u >> 4, i = u & 15;
      s = fmaf(S_l[u], W2g[c * (IN_NODE * OUT_NODE) + i * OUT_NODE + o], s);
    }
    if (lane < 16) {
      s = fmaf(xs_l[lane], b2g[lane * OUT_NODE + o], s);
      s = fmaf(xn_f[lane], rootg[lane * OUT_NODE + o], s);
    }
    ROW_SUM16(s);
    s += __shfl_xor(s, 16, 64);
    s += __shfl_xor(s, 32, 64);
    if (lane == 0) pooled[o] = s * invc + biasg[o];
  }
  __syncthreads();

  {
    float v = ab1[tid];
#pragma unroll
    for (int k = 0; k < OUT_NODE; ++k)
      v = fmaf(pooled[k], A1[k * HA + tid], v);
    a_s[tid] = fmaxf(v, 0.f);
  }
  __syncthreads();
  {
    const int j = tid & 15, seg = tid >> 4;
    float v = 0.f;
#pragma unroll
    for (int kk = 0; kk < 16; ++kk) {
      const int k = seg * 16 + kk;
      v += a_s[k] * A2[k * N_ACT + j];
    }
    red[seg][j] = v;
  }
  __syncthreads();
  if (tid < N_ACT) {
    float s = ab2[tid];
#pragma unroll
    for (int seg = 0; seg < 16; ++seg) s += red[seg][tid];
    out[g * N_ACT + tid] = s;
  }
}

// ---------------------------------------------------------------------------
extern "C" void kernel_launch(void* const* d_in, const int* in_sizes, int n_in,
                              void* d_out, int out_size, void* d_ws,
                              size_t ws_size, hipStream_t stream) {
  const float* x     = (const float*)d_in[0];
  const int*   ei    = (const int*)d_in[1];
  const float* ea    = (const float*)d_in[2];
  const int*   batch = (const int*)d_in[3];
  const float* W1    = (const float*)d_in[4];
  const float* b1    = (const float*)d_in[5];
  const float* gamma = (const float*)d_in[6];
  const float* beta  = (const float*)d_in[7];
  const float* W2    = (const float*)d_in[8];
  const float* b2    = (const float*)d_in[9];
  const float* root  = (const float*)d_in[10];
  const float* bias  = (const float*)d_in[11];
  const float* A1    = (const float*)d_in[12];
  const float* ab1   = (const float*)d_in[13];
  const float* A2    = (const float*)d_in[14];
  const float* ab2   = (const float*)d_in[15];
  float* out = (float*)d_out;

  float* ws = (float*)d_ws;
  int*   iw = (int*)d_ws;
  // float-word offsets
  float* hdr    = ws;                 // [0:128)
  float* scale  = ws + 128;           // [128:192)
  float* c1     = ws + 192;           // [192:256)
  float* XN     = ws + 256;           // [256:2304)  128*16
  float* cntb   = ws + 2304;          // [2304:2432)
  int*   hist   = iw + 2432;          // [2432:2560) int
  // --- zeroed through 2560 words ---
  int*   bstart = iw + 2560;          // 129 ints (+pad)
  int*   cursor = iw + 2696;          // 128 ints
  int*   ge     = iw + 2824;          // 400000 ints
  int*   perm   = iw + 402824;        // 400000 ints
  float* Spart  = ws + 802824;        // 512*1024
  float* XSpart = ws + 1327112;       // 512*16

  hipMemsetAsync(d_ws, 0, 2560 * sizeof(float), stream);

  bn_stats<<<256, 256, 0, stream>>>(ea, hdr);
  bn_finalize<<<1, 64, 0, stream>>>(hdr, W1, b1, gamma, beta, scale, c1);
  hist_g<<<256, 256, 0, stream>>>(ei, batch, ge, hist);
  scan_k<<<1, 128, 0, stream>>>(hist, bstart, cursor);
  scatter_k<<<256, 256, 0, stream>>>(ge, cursor, perm);
  s_kernel<<<N_GRAPHS * SPLIT, 256, 0, stream>>>(x, ei, ea, W1, scale, c1,
                                                 perm, bstart, Spart, XSpart);
  xsum_k<<<(N_NODES + 255) / 256, 256, 0, stream>>>(x, batch, XN, cntb);
  fuse_k<<<N_GRAPHS, 256, 0, stream>>>(Spart, XSpart, W2, b2, XN, cntb, root,
                                       bias, A1, ab1, A2, ab2, out);
}

// Round 8
// 86.879 us; speedup vs baseline: 12.0568x; 1.2015x over previous
//
#include <hip/hip_runtime.h>

#define N_NODES   50000
#define N_EDGES   400000
#define IN_NODE   16
#define OUT_NODE  20
#define IN_EDGE   10
#define HE        64
#define HA        256
#define N_ACT     16
#define N_GRAPHS  128
#define BN_EPS    1e-5f
#define HNST      68          // LDS row stride (shorts) for hnT/xT
#define SPLIT     16          // S-kernel blocks per graph

typedef __attribute__((ext_vector_type(8))) short short8v;
typedef __attribute__((ext_vector_type(4))) float f32x4;

__device__ __forceinline__ unsigned short f2bf(float f) {
  unsigned u = __float_as_uint(f);
  u += 0x7fffu + ((u >> 16) & 1u);  // RNE
  return (unsigned short)(u >> 16);
}
__device__ __forceinline__ float bf2f(short s) {
  return __uint_as_float(((unsigned)(unsigned short)s) << 16);
}

#define DPP_ROR_ADD(v, CTRL)                                                  \
  ((v) + __int_as_float(__builtin_amdgcn_update_dpp(                          \
             0, __float_as_int(v), (CTRL), 0xF, 0xF, true)))
#define ROW_SUM16(v)                                                          \
  do {                                                                        \
    v = DPP_ROR_ADD(v, 0x128);                                                \
    v = DPP_ROR_ADD(v, 0x124);                                                \
    v = DPP_ROR_ADD(v, 0x122);                                                \
    v = DPP_ROR_ADD(v, 0x121);                                                \
  } while (0)

// ---------------------------------------------------------------------------
// Kernel 1 (merged bn_stats + hist_g): one edge-streaming pass computing
//  (a) BN Gram stats of ea (colsum + upper-tri 10x10 Gram -> hdr)
//  (b) per-edge graph id ge[e] = batch[dst[e]] + histogram.
// ---------------------------------------------------------------------------
__global__ __launch_bounds__(256) void prep_k(const float* __restrict__ ea,
                                              const int* __restrict__ ei,
                                              const int* __restrict__ batch,
                                              float* __restrict__ hdr,
                                              int* __restrict__ ge,
                                              int* __restrict__ hist) {
  __shared__ float red[4][72];
  __shared__ int lh[N_GRAPHS];
  float cs[10];
  float gm[55];
#pragma unroll
  for (int a = 0; a < 10; ++a) cs[a] = 0.f;
#pragma unroll
  for (int u = 0; u < 55; ++u) gm[u] = 0.f;
  for (int t = threadIdx.x; t < N_GRAPHS; t += 256) lh[t] = 0;
  __syncthreads();

  for (int e = blockIdx.x * 256 + threadIdx.x; e < N_EDGES; e += 256 * 256) {
    // hist part
    const int g = batch[ei[N_EDGES + e]];
    ge[e] = g;
    atomicAdd(&lh[g], 1);
    // gram part
    const float2* rp = reinterpret_cast<const float2*>(ea + (size_t)e * 10);
    float f[10];
#pragma unroll
    for (int p = 0; p < 5; ++p) {
      const float2 t = rp[p];
      f[2 * p] = t.x;
      f[2 * p + 1] = t.y;
    }
#pragma unroll
    for (int a = 0; a < 10; ++a) cs[a] += f[a];
    int idx = 0;
#pragma unroll
    for (int a = 0; a < 10; ++a)
#pragma unroll
      for (int b = a; b < 10; ++b) {
        gm[idx] = fmaf(f[a], f[b], gm[idx]);
        ++idx;
      }
  }

#pragma unroll
  for (int v = 0; v < 10; ++v)
#pragma unroll
    for (int off = 1; off < 64; off <<= 1) cs[v] += __shfl_xor(cs[v], off, 64);
#pragma unroll
  for (int u = 0; u < 55; ++u)
#pragma unroll
    for (int off = 1; off < 64; off <<= 1) gm[u] += __shfl_xor(gm[u], off, 64);

  const int lane = threadIdx.x & 63;
  const int w = threadIdx.x >> 6;
  if (lane == 0) {
#pragma unroll
    for (int v = 0; v < 10; ++v) red[w][v] = cs[v];
#pragma unroll
    for (int u = 0; u < 55; ++u) red[w][10 + u] = gm[u];
  }
  __syncthreads();
  if (threadIdx.x < 65) {
    const int t = threadIdx.x;
    const float s = red[0][t] + red[1][t] + red[2][t] + red[3][t];
    const int dst = (t < 10) ? t : 6 + t;  // gram at hdr[16+..]
    atomicAdd(&hdr[dst], s);
  }
  if (threadIdx.x < N_GRAPHS && lh[threadIdx.x] > 0)
    atomicAdd(&hist[threadIdx.x], lh[threadIdx.x]);
}

// ---------------------------------------------------------------------------
// Kernel 2 (merged scan + bn_finalize). 1 block, 128 threads.
// ---------------------------------------------------------------------------
__global__ void scan_fin_k(const int* __restrict__ hist,
                           int* __restrict__ bstart, int* __restrict__ cursor,
                           const float* __restrict__ hdr,
                           const float* __restrict__ W1,
                           const float* __restrict__ b1,
                           const float* __restrict__ gamma,
                           const float* __restrict__ beta,
                           float* __restrict__ scale,
                           float* __restrict__ c1out) {
  __shared__ int v[N_GRAPHS];
  const int t = threadIdx.x;
  const int h = hist[t];
  v[t] = h;
  __syncthreads();
  for (int off = 1; off < N_GRAPHS; off <<= 1) {
    int y = 0;
    if (t >= off) y = v[t - off];
    __syncthreads();
    v[t] += y;
    __syncthreads();
  }
  bstart[t] = v[t] - h;
  cursor[t] = v[t] - h;
  if (t == N_GRAPHS - 1) bstart[N_GRAPHS] = v[t];

  if (t < HE) {
    const int c = t;
    float wc[10];
#pragma unroll
    for (int k = 0; k < 10; ++k) wc[k] = W1[k * HE + c];
    float su = 0.f;
#pragma unroll
    for (int k = 0; k < 10; ++k) su = fmaf(hdr[k], wc[k], su);
    float q = 0.f;
    int idx = 0;
#pragma unroll
    for (int a = 0; a < 10; ++a) {
      q = fmaf(hdr[16 + idx], wc[a] * wc[a], q);
      ++idx;
#pragma unroll
      for (int b = a + 1; b < 10; ++b) {
        q = fmaf(2.f * hdr[16 + idx], wc[a] * wc[b], q);
        ++idx;
      }
    }
    const float b1c = b1[c];
    const float invE = 1.f / (float)N_EDGES;
    const float mu = su * invE + b1c;
    const float Eh2 = (q + 2.f * b1c * su) * invE + b1c * b1c;
    const float var = Eh2 - mu * mu;
    const float sc = gamma[c] * rsqrtf(var + BN_EPS);
    scale[c] = sc;
    c1out[c] = sc * (b1c - mu) + beta[c];
  }
}

// ---------------------------------------------------------------------------
// Kernel 3: scatter edges into graph buckets; also emit psrc[slot] = src node
// (kills one indirection level in s_kernel's gather chain).
// ---------------------------------------------------------------------------
__global__ __launch_bounds__(256) void scatter_k(const int* __restrict__ ge,
                                                 const int* __restrict__ ei,
                                                 int* __restrict__ cursor,
                                                 int* __restrict__ perm,
                                                 int* __restrict__ psrc) {
  __shared__ int lh[N_GRAPHS];
  __shared__ int gb[N_GRAPHS];
  for (int t = threadIdx.x; t < N_GRAPHS; t += 256) lh[t] = 0;
  __syncthreads();
  int gj[7], lr[7], ej[7];
#pragma unroll
  for (int j = 0; j < 7; ++j) {
    const int e = blockIdx.x * 256 + threadIdx.x + j * 65536;
    ej[j] = e;
    gj[j] = -1;
    lr[j] = 0;
    if (e < N_EDGES) {
      const int g = ge[e];
      gj[j] = g;
      lr[j] = atomicAdd(&lh[g], 1);
    }
  }
  __syncthreads();
  if (threadIdx.x < N_GRAPHS && lh[threadIdx.x] > 0)
    gb[threadIdx.x] = atomicAdd(&cursor[threadIdx.x], lh[threadIdx.x]);
  __syncthreads();
#pragma unroll
  for (int j = 0; j < 7; ++j)
    if (gj[j] >= 0) {
      const int pos = gb[gj[j]] + lr[j];
      perm[pos] = ej[j];
      psrc[pos] = ei[ej[j]];
    }
}

// ---------------------------------------------------------------------------
// Kernel 4: S accumulation + in-block W2 contraction.
//  Per 64-edge tile: hn via MFMA (ea bf16, K pad 10->32) -> LDS; x gathered
//  via psrc -> LDS (bf16, transposed); MFMA accumulates S[c,i] per lane.
//  Block end: msg_part[o] = sum_{c,i} S*W2' + XS.b2 contracted in-register,
//  block-reduced, 20 floats written. No big partial buffers.
// ---------------------------------------------------------------------------
__global__ __launch_bounds__(256) void s_kernel(
    const float* __restrict__ x, const float* __restrict__ ea,
    const float* __restrict__ W1g, const float* __restrict__ W2g,
    const float* __restrict__ b2g, const float* __restrict__ scale,
    const float* __restrict__ c1g, const int* __restrict__ perm,
    const int* __restrict__ psrc, const int* __restrict__ bstart,
    float* __restrict__ MSGpart) {
  __shared__ short hnT[2][64 * HNST];  // [c][e]
  __shared__ short xT[2][16 * HNST];   // [i][e]
  __shared__ float mred[4][OUT_NODE];

  const int tid = threadIdx.x;
  const int lane = tid & 63;
  const int w = tid >> 6;
  const int i_col = lane & 15;
  const int kq = lane >> 4;

  const int g = blockIdx.x / SPLIT;
  const int pp = blockIdx.x - g * SPLIT;
  const int gs = bstart[g], geE = bstart[g + 1];
  const int cnt = geE - gs;
  const int p0 = gs + (cnt * pp) / SPLIT;
  const int p1 = gs + (cnt * (pp + 1)) / SPLIT;

  short8v w1f[4];
  float scv[4], c1v[4];
#pragma unroll
  for (int nt = 0; nt < 4; ++nt) {
    short8v v;
#pragma unroll
    for (int j = 0; j < 8; ++j) {
      const int k = kq * 8 + j;
      const float f = (k < IN_EDGE) ? W1g[k * HE + nt * 16 + i_col] : 0.f;
      v[j] = (short)f2bf(f);
    }
    w1f[nt] = v;
    scv[nt] = scale[nt * 16 + i_col];
    c1v[nt] = c1g[nt * 16 + i_col];
  }

  f32x4 acc = {0.f, 0.f, 0.f, 0.f};
  float xs = 0.f;

  int p = 0;
  for (int base = p0; base < p1; base += 64) {
    // ---- produce hn (wave w: edges base+w*16 .. +15) ----
    {
      const int er = base + w * 16 + i_col;
      const bool val = er < p1;
      const int pe = val ? perm[er] : 0;
      const float* row = ea + (size_t)pe * IN_EDGE;
      float af[8];
#pragma unroll
      for (int j = 0; j < 8; ++j) af[j] = 0.f;
      if (val) {
#pragma unroll
        for (int pr = 0; pr < 4; ++pr) {
          const int k = kq * 8 + pr * 2;
          if (k < IN_EDGE) {
            const float2 t2 = *reinterpret_cast<const float2*>(row + k);
            af[pr * 2] = t2.x;
            af[pr * 2 + 1] = t2.y;
          }
        }
      }
      short8v ae;
#pragma unroll
      for (int j = 0; j < 8; ++j) ae[j] = (short)f2bf(af[j]);

      const f32x4 zero4 = {0.f, 0.f, 0.f, 0.f};
#pragma unroll
      for (int nt = 0; nt < 4; ++nt) {
        const f32x4 hv = __builtin_amdgcn_mfma_f32_16x16x32_bf16(
            ae, w1f[nt], zero4, 0, 0, 0);
        short4 sv;
        {
          const int e0 = base + w * 16 + kq * 4;
          const float h0 = (e0 + 0 < p1) ? fmaxf(fmaf(hv[0], scv[nt], c1v[nt]), 0.f) : 0.f;
          const float h1 = (e0 + 1 < p1) ? fmaxf(fmaf(hv[1], scv[nt], c1v[nt]), 0.f) : 0.f;
          const float h2 = (e0 + 2 < p1) ? fmaxf(fmaf(hv[2], scv[nt], c1v[nt]), 0.f) : 0.f;
          const float h3 = (e0 + 3 < p1) ? fmaxf(fmaf(hv[3], scv[nt], c1v[nt]), 0.f) : 0.f;
          sv.x = (short)f2bf(h0);
          sv.y = (short)f2bf(h1);
          sv.z = (short)f2bf(h2);
          sv.w = (short)f2bf(h3);
        }
        *reinterpret_cast<short4*>(
            &hnT[p][(nt * 16 + i_col) * HNST + w * 16 + kq * 4]) = sv;
      }
    }
    // ---- stage xT via psrc (2-level chain, parallel with ea) ----
    {
      const int et = tid >> 2, iq = tid & 3;
      const int er = base + et;
      float4 xv = {0.f, 0.f, 0.f, 0.f};
      if (er < p1) {
        const int s = psrc[er];
        xv = *reinterpret_cast<const float4*>(&x[(size_t)s * IN_NODE + iq * 4]);
      }
      xT[p][(iq * 4 + 0) * HNST + et] = (short)f2bf(xv.x);
      xT[p][(iq * 4 + 1) * HNST + et] = (short)f2bf(xv.y);
      xT[p][(iq * 4 + 2) * HNST + et] = (short)f2bf(xv.z);
      xT[p][(iq * 4 + 3) * HNST + et] = (short)f2bf(xv.w);
    }
    __syncthreads();
#pragma unroll
    for (int ks = 0; ks < 2; ++ks) {
      const short8v a = *reinterpret_cast<const short8v*>(
          &hnT[p][(w * 16 + i_col) * HNST + ks * 32 + kq * 8]);
      const short8v b = *reinterpret_cast<const short8v*>(
          &xT[p][i_col * HNST + ks * 32 + kq * 8]);
      acc = __builtin_amdgcn_mfma_f32_16x16x32_bf16(a, b, acc, 0, 0, 0);
      if (w == 0) {
#pragma unroll
        for (int j = 0; j < 8; ++j) xs += bf2f(b[j]);
      }
    }
    p ^= 1;
  }

  // ---- in-block contraction: msg[o] = sum S[c,i]*W2[c,i,o] (+ XS.b2) ----
  if (w == 0) {
    xs += __shfl_xor(xs, 16, 64);
    xs += __shfl_xor(xs, 32, 64);
  }
  float po[OUT_NODE];
#pragma unroll
  for (int o = 0; o < OUT_NODE; ++o) po[o] = 0.f;
#pragma unroll
  for (int r = 0; r < 4; ++r) {
    const float* w2p =
        &W2g[(size_t)(w * 16 + kq * 4 + r) * (IN_NODE * OUT_NODE) +
             i_col * OUT_NODE];
#pragma unroll
    for (int o = 0; o < OUT_NODE; ++o) po[o] = fmaf(acc[r], w2p[o], po[o]);
  }
  if (w == 0 && kq == 0) {
    const float* b2p = &b2g[i_col * OUT_NODE];
#pragma unroll
    for (int o = 0; o < OUT_NODE; ++o) po[o] = fmaf(xs, b2p[o], po[o]);
  }
#pragma unroll
  for (int o = 0; o < OUT_NODE; ++o) {
    float s = po[o];
    ROW_SUM16(s);
    s += __shfl_xor(s, 16, 64);
    s += __shfl_xor(s, 32, 64);
    po[o] = s;
  }
  if (lane == 0) {
#pragma unroll
    for (int o = 0; o < OUT_NODE; ++o) mred[w][o] = po[o];
  }
  __syncthreads();
  if (tid < OUT_NODE)
    MSGpart[(size_t)blockIdx.x * OUT_NODE + tid] =
        mred[0][tid] + mred[1][tid] + mred[2][tid] + mred[3][tid];
}

// ---------------------------------------------------------------------------
// Kernel 5: XN[g][i] = sum_{n in g} x[n][i]; cnt[g]. (unchanged from R7)
// ---------------------------------------------------------------------------
__global__ __launch_bounds__(256) void xsum_k(const float* __restrict__ x,
                                              const int* __restrict__ batch,
                                              float* __restrict__ XN,
                                              float* __restrict__ cnt) {
  __shared__ float xn_l[N_GRAPHS * IN_NODE];
  __shared__ float cnt_l[N_GRAPHS];
  const int tid = threadIdx.x;
  const int lane = tid & 63;
  for (int t = tid; t < N_GRAPHS * IN_NODE; t += 256) xn_l[t] = 0.f;
  if (tid < N_GRAPHS) cnt_l[tid] = 0.f;
  __syncthreads();

  const int n = blockIdx.x * 256 + tid;
  const bool valid = n < N_NODES;
  int g = -1;
  float xf[IN_NODE];
  if (valid) {
    g = batch[n];
    const float4* xp = reinterpret_cast<const float4*>(&x[(size_t)n * IN_NODE]);
    const float4 a0 = xp[0], a1 = xp[1], a2 = xp[2], a3 = xp[3];
    xf[0] = a0.x;  xf[1] = a0.y;  xf[2] = a0.z;  xf[3] = a0.w;
    xf[4] = a1.x;  xf[5] = a1.y;  xf[6] = a1.z;  xf[7] = a1.w;
    xf[8] = a2.x;  xf[9] = a2.y;  xf[10] = a2.z; xf[11] = a2.w;
    xf[12] = a3.x; xf[13] = a3.y; xf[14] = a3.z; xf[15] = a3.w;
  } else {
#pragma unroll
    for (int i = 0; i < IN_NODE; ++i) xf[i] = 0.f;
  }

  const int g0 = __builtin_amdgcn_readfirstlane(g);
  const bool uni = (__ballot(valid && (g == g0)) == 0xFFFFFFFFFFFFFFFFull);

  if (uni) {
#pragma unroll
    for (int i = 0; i < IN_NODE; ++i) {
      float s = xf[i];
      ROW_SUM16(s);
      s += __shfl_xor(s, 16, 64);
      s += __shfl_xor(s, 32, 64);
      xf[i] = s;
    }
    if (lane == 0) {
#pragma unroll
      for (int i = 0; i < IN_NODE; ++i) atomicAdd(&xn_l[g0 * IN_NODE + i], xf[i]);
      atomicAdd(&cnt_l[g0], 64.f);
    }
  } else if (valid) {
#pragma unroll
    for (int i = 0; i < IN_NODE; ++i) atomicAdd(&xn_l[g * IN_NODE + i], xf[i]);
    atomicAdd(&cnt_l[g], 1.f);
  }
  __syncthreads();

  if (tid < N_GRAPHS && cnt_l[tid] != 0.f) atomicAdd(&cnt[tid], cnt_l[tid]);
  for (int t = tid; t < N_GRAPHS * IN_NODE; t += 256) {
    const float v = xn_l[t];
    if (v != 0.f) atomicAdd(&XN[t], v);
  }
}

// ---------------------------------------------------------------------------
// Kernel 6: fuse. pooled[o] = (sum msg_part + XN@root)/cnt + bias; actor MLP.
// ---------------------------------------------------------------------------
__global__ __launch_bounds__(256) void fuse_k(
    const float* __restrict__ MSGpart, const float* __restrict__ XN,
    const float* __restrict__ cnt, const float* __restrict__ rootg,
    const float* __restrict__ biasg, const float* __restrict__ A1,
    const float* __restrict__ ab1, const float* __restrict__ A2,
    const float* __restrict__ ab2, float* __restrict__ out) {
  __shared__ float pooled[OUT_NODE];
  __shared__ float a_s[HA];
  __shared__ float red[16][N_ACT];

  const int g = blockIdx.x;
  const int tid = threadIdx.x;
  if (tid < OUT_NODE) {
    float s = 0.f;
#pragma unroll
    for (int q = 0; q < SPLIT; ++q)
      s += MSGpart[(size_t)(g * SPLIT + q) * OUT_NODE + tid];
#pragma unroll
    for (int i = 0; i < IN_NODE; ++i)
      s = fmaf(XN[g * IN_NODE + i], rootg[i * OUT_NODE + tid], s);
    const float invc = 1.f / fmaxf(cnt[g], 1.f);
    pooled[tid] = s * invc + biasg[tid];
  }
  __syncthreads();

  {
    float v = ab1[tid];
#pragma unroll
    for (int k = 0; k < OUT_NODE; ++k) v = fmaf(pooled[k], A1[k * HA + tid], v);
    a_s[tid] = fmaxf(v, 0.f);
  }
  __syncthreads();
  {
    const int j = tid & 15, seg = tid >> 4;
    float v = 0.f;
#pragma unroll
    for (int kk = 0; kk < 16; ++kk) {
      const int k = seg * 16 + kk;
      v += a_s[k] * A2[k * N_ACT + j];
    }
    red[seg][j] = v;
  }
  __syncthreads();
  if (tid < N_ACT) {
    float s = ab2[tid];
#pragma unroll
    for (int seg = 0; seg < 16; ++seg) s += red[seg][tid];
    out[g * N_ACT + tid] = s;
  }
}

// ---------------------------------------------------------------------------
extern "C" void kernel_launch(void* const* d_in, const int* in_sizes, int n_in,
                              void* d_out, int out_size, void* d_ws,
                              size_t ws_size, hipStream_t stream) {
  const float* x     = (const float*)d_in[0];
  const int*   ei    = (const int*)d_in[1];
  const float* ea    = (const float*)d_in[2];
  const int*   batch = (const int*)d_in[3];
  const float* W1    = (const float*)d_in[4];
  const float* b1    = (const float*)d_in[5];
  const float* gamma = (const float*)d_in[6];
  const float* beta  = (const float*)d_in[7];
  const float* W2    = (const float*)d_in[8];
  const float* b2    = (const float*)d_in[9];
  const float* root  = (const float*)d_in[10];
  const float* bias  = (const float*)d_in[11];
  const float* A1    = (const float*)d_in[12];
  const float* ab1   = (const float*)d_in[13];
  const float* A2    = (const float*)d_in[14];
  const float* ab2   = (const float*)d_in[15];
  float* out = (float*)d_out;

  float* ws = (float*)d_ws;
  int*   iw = (int*)d_ws;
  // word offsets
  float* hdr     = ws;                 // [0:128)
  float* scale   = ws + 128;           // [128:192)
  float* c1      = ws + 192;           // [192:256)
  float* XN      = ws + 256;           // [256:2304)  128*16
  float* cntb    = ws + 2304;          // [2304:2432)
  int*   hist    = iw + 2432;          // [2432:2560) int
  // --- zeroed through 2560 words ---
  int*   bstart  = iw + 2560;          // 129 ints (+pad)
  int*   cursor  = iw + 2696;          // 128 ints
  int*   ge      = iw + 2824;          // 400000
  int*   perm    = iw + 402824;        // 400000
  int*   psrc    = iw + 802824;        // 400000
  float* MSGpart = ws + 1202824;       // 2048*20 = 40960

  hipMemsetAsync(d_ws, 0, 2560 * sizeof(float), stream);

  prep_k<<<256, 256, 0, stream>>>(ea, ei, batch, hdr, ge, hist);
  scan_fin_k<<<1, 128, 0, stream>>>(hist, bstart, cursor, hdr, W1, b1, gamma,
                                    beta, scale, c1);
  scatter_k<<<256, 256, 0, stream>>>(ge, ei, cursor, perm, psrc);
  s_kernel<<<N_GRAPHS * SPLIT, 256, 0, stream>>>(x, ea, W1, W2, b2, scale, c1,
                                                 perm, psrc, bstart, MSGpart);
  xsum_k<<<(N_NODES + 255) / 256, 256, 0, stream>>>(x, batch, XN, cntb);
  fuse_k<<<N_GRAPHS, 256, 0, stream>>>(MSGpart, XN, cntb, root, bias, A1, ab1,
                                       A2, ab2, out);
}

// Round 9
// 84.143 us; speedup vs baseline: 12.4488x; 1.0325x over previous
//
#include <hip/hip_runtime.h>

#define N_NODES   50000
#define N_EDGES   400000
#define IN_NODE   16
#define OUT_NODE  20
#define IN_EDGE   10
#define HE        64
#define HA        256
#define N_ACT     16
#define N_GRAPHS  128
#define BN_EPS    1e-5f
#define HNST      68          // LDS row stride (shorts) for hnT/xT
#define SPLIT     16          // S-kernel blocks per graph

typedef __attribute__((ext_vector_type(8))) short short8v;
typedef __attribute__((ext_vector_type(4))) float f32x4;

__device__ __forceinline__ unsigned short f2bf(float f) {
  unsigned u = __float_as_uint(f);
  u += 0x7fffu + ((u >> 16) & 1u);  // RNE
  return (unsigned short)(u >> 16);
}
__device__ __forceinline__ float bf2f(short s) {
  return __uint_as_float(((unsigned)(unsigned short)s) << 16);
}

#define DPP_ROR_ADD(v, CTRL)                                                  \
  ((v) + __int_as_float(__builtin_amdgcn_update_dpp(                          \
             0, __float_as_int(v), (CTRL), 0xF, 0xF, true)))
#define ROW_SUM16(v)                                                          \
  do {                                                                        \
    v = DPP_ROR_ADD(v, 0x128);                                                \
    v = DPP_ROR_ADD(v, 0x124);                                                \
    v = DPP_ROR_ADD(v, 0x122);                                                \
    v = DPP_ROR_ADD(v, 0x121);                                                \
  } while (0)

// ---------------------------------------------------------------------------
// Kernel 0: zero the small accumulator region (hdr, XN, cnt, hist).
// Replaces hipMemsetAsync's fillBuffer blit with a plain 2 us kernel.
// ---------------------------------------------------------------------------
__global__ void zero_k(float* __restrict__ ws) {
  ws[blockIdx.x * 256 + threadIdx.x] = 0.f;
}

// ---------------------------------------------------------------------------
// Kernel 1: histogram of edges per graph (g = batch[dst[e]]).
// ---------------------------------------------------------------------------
__global__ __launch_bounds__(256) void prep_k(const int* __restrict__ ei,
                                              const int* __restrict__ batch,
                                              int* __restrict__ hist) {
  __shared__ int lh[N_GRAPHS];
  const int tid = threadIdx.x;
  if (tid < N_GRAPHS) lh[tid] = 0;
  __syncthreads();
  for (int e = blockIdx.x * 256 + tid; e < N_EDGES; e += 256 * 256)
    atomicAdd(&lh[batch[ei[N_EDGES + e]]], 1);
  __syncthreads();
  if (tid < N_GRAPHS && lh[tid] > 0) atomicAdd(&hist[tid], lh[tid]);
}

// ---------------------------------------------------------------------------
// Kernel 2: exclusive scan -> bstart[129], cursor init. 1 block, 128 thr.
// ---------------------------------------------------------------------------
__global__ void scan_k(const int* __restrict__ hist, int* __restrict__ bstart,
                       int* __restrict__ cursor) {
  __shared__ int v[N_GRAPHS];
  const int t = threadIdx.x;
  const int h = hist[t];
  v[t] = h;
  __syncthreads();
  for (int off = 1; off < N_GRAPHS; off <<= 1) {
    int y = 0;
    if (t >= off) y = v[t - off];
    __syncthreads();
    v[t] += y;
    __syncthreads();
  }
  bstart[t] = v[t] - h;
  cursor[t] = v[t] - h;
  if (t == N_GRAPHS - 1) bstart[N_GRAPHS] = v[t];
}

// ---------------------------------------------------------------------------
// Kernel 3: scatter-pack + BN Gram stats in one ea-streaming pass.
// Per edge: record exb[slot] (64 B, one cache line) =
//   shorts[0:10) ea bf16, [10:16) zero, [16:32) x[src] bf16.
// Plain scattered full-line stores (no latency chain); Gram accumulated
// from the same ea read -> hdr atomics. Kills perm/psrc indirection.
// ---------------------------------------------------------------------------
__global__ __launch_bounds__(256) void scatter_k(
    const float* __restrict__ ea, const int* __restrict__ ei,
    const int* __restrict__ batch, const float* __restrict__ x,
    int* __restrict__ cursor, unsigned short* __restrict__ exb,
    float* __restrict__ hdr) {
  __shared__ int lh[N_GRAPHS];
  __shared__ int gb[N_GRAPHS];
  __shared__ float red[4][72];
  const int tid = threadIdx.x;

  float cs[10];
  float gm[55];
#pragma unroll
  for (int a = 0; a < 10; ++a) cs[a] = 0.f;
#pragma unroll
  for (int u = 0; u < 55; ++u) gm[u] = 0.f;
  if (tid < N_GRAPHS) lh[tid] = 0;
  __syncthreads();

  int gj[7], lr[7];
#pragma unroll
  for (int j = 0; j < 7; ++j) {
    const int e = blockIdx.x * 256 + tid + j * 65536;
    gj[j] = -1;
    lr[j] = 0;
    if (e < N_EDGES) {
      const int g = batch[ei[N_EDGES + e]];
      gj[j] = g;
      lr[j] = atomicAdd(&lh[g], 1);
    }
  }
  __syncthreads();
  if (tid < N_GRAPHS && lh[tid] > 0)
    gb[tid] = atomicAdd(&cursor[tid], lh[tid]);
  __syncthreads();

#pragma unroll
  for (int j = 0; j < 7; ++j) {
    if (gj[j] < 0) continue;
    const int e = blockIdx.x * 256 + tid + j * 65536;
    // ea row + Gram
    const float2* rp = reinterpret_cast<const float2*>(ea + (size_t)e * 10);
    float f[10];
#pragma unroll
    for (int p = 0; p < 5; ++p) {
      const float2 t2 = rp[p];
      f[2 * p] = t2.x;
      f[2 * p + 1] = t2.y;
    }
#pragma unroll
    for (int a = 0; a < 10; ++a) cs[a] += f[a];
    int idx = 0;
#pragma unroll
    for (int a = 0; a < 10; ++a)
#pragma unroll
      for (int b = a; b < 10; ++b) {
        gm[idx] = fmaf(f[a], f[b], gm[idx]);
        ++idx;
      }
    // x row
    const int s = ei[e];
    const float4* xp = reinterpret_cast<const float4*>(&x[(size_t)s * IN_NODE]);
    const float4 x0 = xp[0], x1 = xp[1], x2 = xp[2], x3 = xp[3];
    // pack 32 shorts = 64 B
    unsigned u[16];
    u[0] = f2bf(f[0]) | ((unsigned)f2bf(f[1]) << 16);
    u[1] = f2bf(f[2]) | ((unsigned)f2bf(f[3]) << 16);
    u[2] = f2bf(f[4]) | ((unsigned)f2bf(f[5]) << 16);
    u[3] = f2bf(f[6]) | ((unsigned)f2bf(f[7]) << 16);
    u[4] = f2bf(f[8]) | ((unsigned)f2bf(f[9]) << 16);
    u[5] = 0; u[6] = 0; u[7] = 0;
    u[8]  = f2bf(x0.x) | ((unsigned)f2bf(x0.y) << 16);
    u[9]  = f2bf(x0.z) | ((unsigned)f2bf(x0.w) << 16);
    u[10] = f2bf(x1.x) | ((unsigned)f2bf(x1.y) << 16);
    u[11] = f2bf(x1.z) | ((unsigned)f2bf(x1.w) << 16);
    u[12] = f2bf(x2.x) | ((unsigned)f2bf(x2.y) << 16);
    u[13] = f2bf(x2.z) | ((unsigned)f2bf(x2.w) << 16);
    u[14] = f2bf(x3.x) | ((unsigned)f2bf(x3.y) << 16);
    u[15] = f2bf(x3.z) | ((unsigned)f2bf(x3.w) << 16);
    const int pos = gb[gj[j]] + lr[j];
    int4* dst = reinterpret_cast<int4*>(exb + (size_t)pos * 32);
    dst[0] = int4{(int)u[0], (int)u[1], (int)u[2], (int)u[3]};
    dst[1] = int4{(int)u[4], (int)u[5], (int)u[6], (int)u[7]};
    dst[2] = int4{(int)u[8], (int)u[9], (int)u[10], (int)u[11]};
    dst[3] = int4{(int)u[12], (int)u[13], (int)u[14], (int)u[15]};
  }

  // Gram reduction -> hdr
#pragma unroll
  for (int v = 0; v < 10; ++v)
#pragma unroll
    for (int off = 1; off < 64; off <<= 1) cs[v] += __shfl_xor(cs[v], off, 64);
#pragma unroll
  for (int u = 0; u < 55; ++u)
#pragma unroll
    for (int off = 1; off < 64; off <<= 1) gm[u] += __shfl_xor(gm[u], off, 64);
  const int lane = tid & 63;
  const int w = tid >> 6;
  if (lane == 0) {
#pragma unroll
    for (int v = 0; v < 10; ++v) red[w][v] = cs[v];
#pragma unroll
    for (int u = 0; u < 55; ++u) red[w][10 + u] = gm[u];
  }
  __syncthreads();
  if (tid < 65) {
    const float s = red[0][tid] + red[1][tid] + red[2][tid] + red[3][tid];
    const int dst = (tid < 10) ? tid : 6 + tid;  // gram at hdr[16+..]
    atomicAdd(&hdr[dst], s);
  }
}

// ---------------------------------------------------------------------------
// Kernel 4: S accumulation + in-block W2 contraction. All loads coalesced
// from exb; BN affine computed in-block from hdr (no fin dispatch).
// ---------------------------------------------------------------------------
__global__ __launch_bounds__(256, 2) void s_kernel(
    const unsigned short* __restrict__ exb, const float* __restrict__ W1g,
    const float* __restrict__ W2g, const float* __restrict__ b2g,
    const float* __restrict__ b1, const float* __restrict__ gamma,
    const float* __restrict__ beta, const float* __restrict__ hdr,
    const int* __restrict__ bstart, float* __restrict__ MSGpart) {
  __shared__ short hnT[2][64 * HNST];  // [c][e]
  __shared__ short xT[2][16 * HNST];   // [i][e]
  __shared__ float mred[4][OUT_NODE];
  __shared__ float scs[HE], c1s[HE];

  const int tid = threadIdx.x;
  const int lane = tid & 63;
  const int w = tid >> 6;
  const int i_col = lane & 15;
  const int kq = lane >> 4;

  // BN affine from Gram header (per block; L2-hot, ~70 FLOP/channel)
  if (tid < HE) {
    const int c = tid;
    float wc[10];
#pragma unroll
    for (int k = 0; k < 10; ++k) wc[k] = W1g[k * HE + c];
    float su = 0.f;
#pragma unroll
    for (int k = 0; k < 10; ++k) su = fmaf(hdr[k], wc[k], su);
    float q = 0.f;
    int idx = 0;
#pragma unroll
    for (int a = 0; a < 10; ++a) {
      q = fmaf(hdr[16 + idx], wc[a] * wc[a], q);
      ++idx;
#pragma unroll
      for (int b = a + 1; b < 10; ++b) {
        q = fmaf(2.f * hdr[16 + idx], wc[a] * wc[b], q);
        ++idx;
      }
    }
    const float b1c = b1[c];
    const float invE = 1.f / (float)N_EDGES;
    const float mu = su * invE + b1c;
    const float Eh2 = (q + 2.f * b1c * su) * invE + b1c * b1c;
    const float var = Eh2 - mu * mu;
    const float sc = gamma[c] * rsqrtf(var + BN_EPS);
    scs[c] = sc;
    c1s[c] = sc * (b1c - mu) + beta[c];
  }
  __syncthreads();

  const int g = blockIdx.x / SPLIT;
  const int pp = blockIdx.x - g * SPLIT;
  const int gs = bstart[g], geE = bstart[g + 1];
  const int cnt = geE - gs;
  const int p0 = gs + (cnt * pp) / SPLIT;
  const int p1 = gs + (cnt * (pp + 1)) / SPLIT;

  short8v w1f[4];
  float scv[4], c1v[4];
#pragma unroll
  for (int nt = 0; nt < 4; ++nt) {
    short8v v;
#pragma unroll
    for (int j = 0; j < 8; ++j) {
      const int k = kq * 8 + j;
      const float f = (k < IN_EDGE) ? W1g[k * HE + nt * 16 + i_col] : 0.f;
      v[j] = (short)f2bf(f);
    }
    w1f[nt] = v;
    scv[nt] = scs[nt * 16 + i_col];
    c1v[nt] = c1s[nt * 16 + i_col];
  }

  f32x4 acc = {0.f, 0.f, 0.f, 0.f};
  float xs = 0.f;

  int p = 0;
  for (int base = p0; base < p1; base += 64) {
    // ---- produce hn: coalesced ea-frag load from exb ----
    {
      const int er = base + w * 16 + i_col;
      short8v ae;
      if (kq < 2) {
        ae = *reinterpret_cast<const short8v*>(&exb[(size_t)er * 32 + kq * 8]);
      } else {
#pragma unroll
        for (int j = 0; j < 8; ++j) ae[j] = 0;
      }
      const f32x4 zero4 = {0.f, 0.f, 0.f, 0.f};
#pragma unroll
      for (int nt = 0; nt < 4; ++nt) {
        const f32x4 hv = __builtin_amdgcn_mfma_f32_16x16x32_bf16(
            ae, w1f[nt], zero4, 0, 0, 0);
        short4 sv;
        {
          const int e0 = base + w * 16 + kq * 4;
          const float h0 = (e0 + 0 < p1) ? fmaxf(fmaf(hv[0], scv[nt], c1v[nt]), 0.f) : 0.f;
          const float h1 = (e0 + 1 < p1) ? fmaxf(fmaf(hv[1], scv[nt], c1v[nt]), 0.f) : 0.f;
          const float h2 = (e0 + 2 < p1) ? fmaxf(fmaf(hv[2], scv[nt], c1v[nt]), 0.f) : 0.f;
          const float h3 = (e0 + 3 < p1) ? fmaxf(fmaf(hv[3], scv[nt], c1v[nt]), 0.f) : 0.f;
          sv.x = (short)f2bf(h0);
          sv.y = (short)f2bf(h1);
          sv.z = (short)f2bf(h2);
          sv.w = (short)f2bf(h3);
        }
        *reinterpret_cast<short4*>(
            &hnT[p][(nt * 16 + i_col) * HNST + w * 16 + kq * 4]) = sv;
      }
    }
    // ---- stage xT: coalesced 8B load from exb ----
    {
      const int et = tid >> 2, iq = tid & 3;
      const int er = base + et;
      short4 xv = {0, 0, 0, 0};
      if (er < p1)
        xv = *reinterpret_cast<const short4*>(
            &exb[(size_t)er * 32 + 16 + iq * 4]);
      xT[p][(iq * 4 + 0) * HNST + et] = xv.x;
      xT[p][(iq * 4 + 1) * HNST + et] = xv.y;
      xT[p][(iq * 4 + 2) * HNST + et] = xv.z;
      xT[p][(iq * 4 + 3) * HNST + et] = xv.w;
    }
    __syncthreads();
#pragma unroll
    for (int ks = 0; ks < 2; ++ks) {
      const short8v a = *reinterpret_cast<const short8v*>(
          &hnT[p][(w * 16 + i_col) * HNST + ks * 32 + kq * 8]);
      const short8v b = *reinterpret_cast<const short8v*>(
          &xT[p][i_col * HNST + ks * 32 + kq * 8]);
      acc = __builtin_amdgcn_mfma_f32_16x16x32_bf16(a, b, acc, 0, 0, 0);
      if (w == 0) {
#pragma unroll
        for (int j = 0; j < 8; ++j) xs += bf2f(b[j]);
      }
    }
    p ^= 1;
  }

  // ---- in-block contraction: msg[o] = sum S[c,i]*W2[c,i,o] (+ XS.b2) ----
  if (w == 0) {
    xs += __shfl_xor(xs, 16, 64);
    xs += __shfl_xor(xs, 32, 64);
  }
  float po[OUT_NODE];
#pragma unroll
  for (int o = 0; o < OUT_NODE; ++o) po[o] = 0.f;
#pragma unroll
  for (int r = 0; r < 4; ++r) {
    const float* w2p =
        &W2g[(size_t)(w * 16 + kq * 4 + r) * (IN_NODE * OUT_NODE) +
             i_col * OUT_NODE];
#pragma unroll
    for (int o = 0; o < OUT_NODE; ++o) po[o] = fmaf(acc[r], w2p[o], po[o]);
  }
  if (w == 0 && kq == 0) {
    const float* b2p = &b2g[i_col * OUT_NODE];
#pragma unroll
    for (int o = 0; o < OUT_NODE; ++o) po[o] = fmaf(xs, b2p[o], po[o]);
  }
#pragma unroll
  for (int o = 0; o < OUT_NODE; ++o) {
    float s = po[o];
    ROW_SUM16(s);
    s += __shfl_xor(s, 16, 64);
    s += __shfl_xor(s, 32, 64);
    po[o] = s;
  }
  if (lane == 0) {
#pragma unroll
    for (int o = 0; o < OUT_NODE; ++o) mred[w][o] = po[o];
  }
  __syncthreads();
  if (tid < OUT_NODE)
    MSGpart[(size_t)blockIdx.x * OUT_NODE + tid] =
        mred[0][tid] + mred[1][tid] + mred[2][tid] + mred[3][tid];
}

// ---------------------------------------------------------------------------
// Kernel 5: XN[g][i] = sum_{n in g} x[n][i]; cnt[g]. (unchanged)
// ---------------------------------------------------------------------------
__global__ __launch_bounds__(256) void xsum_k(const float* __restrict__ x,
                                              const int* __restrict__ batch,
                                              float* __restrict__ XN,
                                              float* __restrict__ cnt) {
  __shared__ float xn_l[N_GRAPHS * IN_NODE];
  __shared__ float cnt_l[N_GRAPHS];
  const int tid = threadIdx.x;
  const int lane = tid & 63;
  for (int t = tid; t < N_GRAPHS * IN_NODE; t += 256) xn_l[t] = 0.f;
  if (tid < N_GRAPHS) cnt_l[tid] = 0.f;
  __syncthreads();

  const int n = blockIdx.x * 256 + tid;
  const bool valid = n < N_NODES;
  int g = -1;
  float xf[IN_NODE];
  if (valid) {
    g = batch[n];
    const float4* xp = reinterpret_cast<const float4*>(&x[(size_t)n * IN_NODE]);
    const float4 a0 = xp[0], a1 = xp[1], a2 = xp[2], a3 = xp[3];
    xf[0] = a0.x;  xf[1] = a0.y;  xf[2] = a0.z;  xf[3] = a0.w;
    xf[4] = a1.x;  xf[5] = a1.y;  xf[6] = a1.z;  xf[7] = a1.w;
    xf[8] = a2.x;  xf[9] = a2.y;  xf[10] = a2.z; xf[11] = a2.w;
    xf[12] = a3.x; xf[13] = a3.y; xf[14] = a3.z; xf[15] = a3.w;
  } else {
#pragma unroll
    for (int i = 0; i < IN_NODE; ++i) xf[i] = 0.f;
  }

  const int g0 = __builtin_amdgcn_readfirstlane(g);
  const bool uni = (__ballot(valid && (g == g0)) == 0xFFFFFFFFFFFFFFFFull);

  if (uni) {
#pragma unroll
    for (int i = 0; i < IN_NODE; ++i) {
      float s = xf[i];
      ROW_SUM16(s);
      s += __shfl_xor(s, 16, 64);
      s += __shfl_xor(s, 32, 64);
      xf[i] = s;
    }
    if (lane == 0) {
#pragma unroll
      for (int i = 0; i < IN_NODE; ++i) atomicAdd(&xn_l[g0 * IN_NODE + i], xf[i]);
      atomicAdd(&cnt_l[g0], 64.f);
    }
  } else if (valid) {
#pragma unroll
    for (int i = 0; i < IN_NODE; ++i) atomicAdd(&xn_l[g * IN_NODE + i], xf[i]);
    atomicAdd(&cnt_l[g], 1.f);
  }
  __syncthreads();

  if (tid < N_GRAPHS && cnt_l[tid] != 0.f) atomicAdd(&cnt[tid], cnt_l[tid]);
  for (int t = tid; t < N_GRAPHS * IN_NODE; t += 256) {
    const float v = xn_l[t];
    if (v != 0.f) atomicAdd(&XN[t], v);
  }
}

// ---------------------------------------------------------------------------
// Kernel 6: fuse. pooled[o] = (sum msg_part + XN@root)/cnt + bias; actor MLP.
// ---------------------------------------------------------------------------
__global__ __launch_bounds__(256) void fuse_k(
    const float* __restrict__ MSGpart, const float* __restrict__ XN,
    const float* __restrict__ cnt, const float* __restrict__ rootg,
    const float* __restrict__ biasg, const float* __restrict__ A1,
    const float* __restrict__ ab1, const float* __restrict__ A2,
    const float* __restrict__ ab2, float* __restrict__ out) {
  __shared__ float pooled[OUT_NODE];
  __shared__ float a_s[HA];
  __shared__ float red[16][N_ACT];

  const int g = blockIdx.x;
  const int tid = threadIdx.x;
  if (tid < OUT_NODE) {
    float s = 0.f;
#pragma unroll
    for (int q = 0; q < SPLIT; ++q)
      s += MSGpart[(size_t)(g * SPLIT + q) * OUT_NODE + tid];
#pragma unroll
    for (int i = 0; i < IN_NODE; ++i)
      s = fmaf(XN[g * IN_NODE + i], rootg[i * OUT_NODE + tid], s);
    const float invc = 1.f / fmaxf(cnt[g], 1.f);
    pooled[tid] = s * invc + biasg[tid];
  }
  __syncthreads();

  {
    float v = ab1[tid];
#pragma unroll
    for (int k = 0; k < OUT_NODE; ++k) v = fmaf(pooled[k], A1[k * HA + tid], v);
    a_s[tid] = fmaxf(v, 0.f);
  }
  __syncthreads();
  {
    const int j = tid & 15, seg = tid >> 4;
    float v = 0.f;
#pragma unroll
    for (int kk = 0; kk < 16; ++kk) {
      const int k = seg * 16 + kk;
      v += a_s[k] * A2[k * N_ACT + j];
    }
    red[seg][j] = v;
  }
  __syncthreads();
  if (tid < N_ACT) {
    float s = ab2[tid];
#pragma unroll
    for (int seg = 0; seg < 16; ++seg) s += red[seg][tid];
    out[g * N_ACT + tid] = s;
  }
}

// ---------------------------------------------------------------------------
extern "C" void kernel_launch(void* const* d_in, const int* in_sizes, int n_in,
                              void* d_out, int out_size, void* d_ws,
                              size_t ws_size, hipStream_t stream) {
  const float* x     = (const float*)d_in[0];
  const int*   ei    = (const int*)d_in[1];
  const float* ea    = (const float*)d_in[2];
  const int*   batch = (const int*)d_in[3];
  const float* W1    = (const float*)d_in[4];
  const float* b1    = (const float*)d_in[5];
  const float* gamma = (const float*)d_in[6];
  const float* beta  = (const float*)d_in[7];
  const float* W2    = (const float*)d_in[8];
  const float* b2    = (const float*)d_in[9];
  const float* root  = (const float*)d_in[10];
  const float* bias  = (const float*)d_in[11];
  const float* A1    = (const float*)d_in[12];
  const float* ab1   = (const float*)d_in[13];
  const float* A2    = (const float*)d_in[14];
  const float* ab2   = (const float*)d_in[15];
  float* out = (float*)d_out;

  float* ws = (float*)d_ws;
  int*   iw = (int*)d_ws;
  // word offsets
  float* hdr     = ws;                 // [0:128)   colsum+gram accum
  float* XN      = ws + 256;           // [256:2304)  128*16
  float* cntb    = ws + 2304;          // [2304:2432)
  int*   hist    = iw + 2432;          // [2432:2560)
  // --- zero_k covers words [0, 2560) ---
  int*   bstart  = iw + 2560;          // 129 ints (+pad)
  int*   cursor  = iw + 2696;          // 128 ints
  float* MSGpart = ws + 2824;          // 2048*20 = 40960 words
  unsigned short* exb = (unsigned short*)(iw + 402824);  // (400000+64)*32 shorts

  zero_k<<<10, 256, 0, stream>>>(ws);
  prep_k<<<256, 256, 0, stream>>>(ei, batch, hist);
  scan_k<<<1, 128, 0, stream>>>(hist, bstart, cursor);
  scatter_k<<<256, 256, 0, stream>>>(ea, ei, batch, x, cursor, exb, hdr);
  s_kernel<<<N_GRAPHS * SPLIT, 256, 0, stream>>>(exb, W1, W2, b2, b1, gamma,
                                                 beta, hdr, bstart, MSGpart);
  xsum_k<<<(N_NODES + 255) / 256, 256, 0, stream>>>(x, batch, XN, cntb);
  fuse_k<<<N_GRAPHS, 256, 0, stream>>>(MSGpart, XN, cntb, root, bias, A1, ab1,
                                       A2, ab2, out);
}